// Round 5
// baseline (1291.714 us; speedup 1.0000x reference)
//
#include <hip/hip_runtime.h>
#include <hip/hip_bf16.h>
#include <cstdint>

// Mamba block fwd, B=2 L=2048 d_model=1024 d_inner=2048 n=16 dt_rank=64 d_conv=4
// Round 5: resubmit of audited fp32 baseline (round-4 file never compiled or
// ran: GPU acquisition timeout). fp32 GEMMs + chunked two-pass selective scan.
//
// Workspace layout (floats), total 45,481,984 f = 173.5 MiB:
//   xz   [4096][4096]  x @ W_in  (cols 0..2047 = xi, 2048..4095 = res)
//   xc   [4096][2048]  silu(conv(xi)+b)
//   xdbl [4096][96]    xc @ W_x  (0..63 dt_in, 64..79 B, 80..95 C)
//   delta[4096][2048]  softplus(dt_in @ W_dt + b_dt)
//   yg   [4096][2048]  scan output, gated:  (y + xc*D) * silu(res)
//   Pbuf/Qbuf/Hini [b][c][n][d]  chunked-scan state (4 MiB each)

#define B_    2
#define L_    2048
#define DMODEL 1024
#define DINNER 2048
#define DSTATE 16
#define DTRANK 64
#define NC    16     // chunks
#define CL    128    // chunk length

__device__ __forceinline__ float sigmoidf_(float x) {
  return 1.f / (1.f + __expf(-x));
}
__device__ __forceinline__ float softplusf_(float x) {
  return fmaxf(x, 0.f) + log1pf(__expf(-fabsf(x)));
}

// ---------------------------------------------------------------------------
// Generic fp32 tiled GEMM: C[M,N] = A[M,K] (row-major, lda) * B[K,N] (ldb)
// 256 threads as 16x16; each thread computes (RG*4)x(CG*4) outputs in groups
// spaced BM/RG rows x BN/CG cols apart.
// EPI: 0 = none, 1 = softplus(acc + bias[col])
// ---------------------------------------------------------------------------
template<int BM, int BN, int BK, int RG, int CG, int EPI>
__launch_bounds__(256)
__global__ void gemm_f32(const float* __restrict__ A, int lda,
                         const float* __restrict__ B, int ldb,
                         float* __restrict__ C, int ldc,
                         int M, int N, int K,
                         const float* __restrict__ bias)
{
  __shared__ float As[BK][BM + 4];
  __shared__ float Bs[BK][BN + 4];

  const int tid = threadIdx.x;
  const int tx = tid & 15;
  const int ty = tid >> 4;
  const int m0 = blockIdx.y * BM;
  const int n0 = blockIdx.x * BN;

  float acc[RG * 4][CG * 4];
#pragma unroll
  for (int i = 0; i < RG * 4; ++i)
#pragma unroll
    for (int j = 0; j < CG * 4; ++j) acc[i][j] = 0.f;

  const int KF4 = BK / 4;
  const int NF4 = BN / 4;

  for (int k0 = 0; k0 < K; k0 += BK) {
#pragma unroll
    for (int j = tid; j < BM * KF4; j += 256) {
      int row = j / KF4, kq = j % KF4;
      float4 v = *(const float4*)&A[(size_t)(m0 + row) * lda + k0 + kq * 4];
      As[kq * 4 + 0][row] = v.x;
      As[kq * 4 + 1][row] = v.y;
      As[kq * 4 + 2][row] = v.z;
      As[kq * 4 + 3][row] = v.w;
    }
#pragma unroll
    for (int j = tid; j < BK * NF4; j += 256) {
      int row = j / NF4, nq = j % NF4;
      int c = n0 + nq * 4;
      float4 v;
      if (c + 3 < N) {
        v = *(const float4*)&B[(size_t)(k0 + row) * ldb + c];
      } else {
        const float* bp = &B[(size_t)(k0 + row) * ldb];
        v.x = (c + 0 < N) ? bp[c + 0] : 0.f;
        v.y = (c + 1 < N) ? bp[c + 1] : 0.f;
        v.z = (c + 2 < N) ? bp[c + 2] : 0.f;
        v.w = (c + 3 < N) ? bp[c + 3] : 0.f;
      }
      *(float4*)&Bs[row][nq * 4] = v;
    }
    __syncthreads();

#pragma unroll
    for (int k = 0; k < BK; ++k) {
      float a[RG][4], b[CG][4];
#pragma unroll
      for (int g = 0; g < RG; ++g) {
        float4 va = *(const float4*)&As[k][g * (BM / RG) + ty * 4];
        a[g][0] = va.x; a[g][1] = va.y; a[g][2] = va.z; a[g][3] = va.w;
      }
#pragma unroll
      for (int h = 0; h < CG; ++h) {
        float4 vb = *(const float4*)&Bs[k][h * (BN / CG) + tx * 4];
        b[h][0] = vb.x; b[h][1] = vb.y; b[h][2] = vb.z; b[h][3] = vb.w;
      }
#pragma unroll
      for (int g = 0; g < RG; ++g)
#pragma unroll
        for (int i = 0; i < 4; ++i)
#pragma unroll
          for (int h = 0; h < CG; ++h)
#pragma unroll
            for (int j = 0; j < 4; ++j)
              acc[g * 4 + i][h * 4 + j] =
                  fmaf(a[g][i], b[h][j], acc[g * 4 + i][h * 4 + j]);
    }
    __syncthreads();
  }

#pragma unroll
  for (int g = 0; g < RG; ++g) {
#pragma unroll
    for (int i = 0; i < 4; ++i) {
      int r = m0 + g * (BM / RG) + ty * 4 + i;
#pragma unroll
      for (int h = 0; h < CG; ++h) {
        int c = n0 + h * (BN / CG) + tx * 4;
        float4 v;
        v.x = acc[g * 4 + i][h * 4 + 0];
        v.y = acc[g * 4 + i][h * 4 + 1];
        v.z = acc[g * 4 + i][h * 4 + 2];
        v.w = acc[g * 4 + i][h * 4 + 3];
        if (c + 3 < N) {
          if (EPI == 1) {
            v.x = softplusf_(v.x + bias[c + 0]);
            v.y = softplusf_(v.y + bias[c + 1]);
            v.z = softplusf_(v.z + bias[c + 2]);
            v.w = softplusf_(v.w + bias[c + 3]);
          }
          *(float4*)&C[(size_t)r * ldc + c] = v;
        } else {
          float vv[4] = {v.x, v.y, v.z, v.w};
#pragma unroll
          for (int j = 0; j < 4; ++j)
            if (c + j < N) {
              float o = vv[j];
              if (EPI == 1) o = softplusf_(o + bias[c + j]);
              C[(size_t)r * ldc + c + j] = o;
            }
        }
      }
    }
  }
}

// ---------------------------------------------------------------------------
// Causal depthwise conv1d (k=4, left-pad 3) + bias + SiLU.
// ---------------------------------------------------------------------------
__launch_bounds__(256)
__global__ void conv_silu(const float* __restrict__ xz,
                          const float* __restrict__ conv_w,
                          const float* __restrict__ conv_b,
                          float* __restrict__ xc)
{
  const int total = B_ * L_ * (DINNER / 4);  // 2^21
  for (int idx = blockIdx.x * blockDim.x + threadIdx.x; idx < total;
       idx += gridDim.x * blockDim.x) {
    int d4 = idx & (DINNER / 4 - 1);
    int l = (idx >> 9) & (L_ - 1);
    int b = idx >> 20;
    int d = d4 * 4;

    float w[4][4];
#pragma unroll
    for (int c = 0; c < 4; ++c) {
      float4 wv = *(const float4*)&conv_w[(d + c) * 4];
      w[c][0] = wv.x; w[c][1] = wv.y; w[c][2] = wv.z; w[c][3] = wv.w;
    }
    float4 bv = *(const float4*)&conv_b[d];
    float s[4] = {bv.x, bv.y, bv.z, bv.w};
#pragma unroll
    for (int t = 0; t < 4; ++t) {
      int ls = l - 3 + t;
      if (ls >= 0) {
        float4 xv =
            *(const float4*)&xz[(size_t)(b * L_ + ls) * (2 * DINNER) + d];
        s[0] = fmaf(w[0][t], xv.x, s[0]);
        s[1] = fmaf(w[1][t], xv.y, s[1]);
        s[2] = fmaf(w[2][t], xv.z, s[2]);
        s[3] = fmaf(w[3][t], xv.w, s[3]);
      }
    }
    float4 o;
    o.x = s[0] * sigmoidf_(s[0]);
    o.y = s[1] * sigmoidf_(s[1]);
    o.z = s[2] * sigmoidf_(s[2]);
    o.w = s[3] * sigmoidf_(s[3]);
    *(float4*)&xc[(size_t)idx * 4] = o;
  }
}

// ---------------------------------------------------------------------------
// Chunked scan pass 1: per (b, chunk, d) compute P[n] = prod(dA), q[n] = local
// scan with h0 = 0. Layout Pbuf/Qbuf[((b*NC+c)*16+n)*DINNER + d] (d coalesced).
// ---------------------------------------------------------------------------
__launch_bounds__(256)
__global__ void scan_pass1(const float* __restrict__ delta,
                           const float* __restrict__ xc,
                           const float* __restrict__ xdbl,
                           const float* __restrict__ A_log,
                           float* __restrict__ Pbuf,
                           float* __restrict__ Qbuf)
{
  const int blk = blockIdx.x;          // b*128 + c*8 + dblk
  const int b = blk >> 7;
  const int c = (blk >> 3) & (NC - 1);
  const int d = ((blk & 7) << 8) + threadIdx.x;

  float An[DSTATE];
#pragma unroll
  for (int n = 0; n < DSTATE; ++n) An[n] = -__expf(A_log[d * DSTATE + n]);

  __shared__ float bs[CL][DSTATE];     // B rows for this chunk (8 KiB)
  const size_t bL = (size_t)b * L_;
  const int l0 = c * CL;
  for (int j = threadIdx.x; j < CL * 4; j += 256) {
    int step = j >> 2, q = j & 3;
    *(float4*)&bs[step][q * 4] =
        *(const float4*)&xdbl[(bL + l0 + step) * 96 + DTRANK + q * 4];
  }
  __syncthreads();

  float P[DSTATE], q[DSTATE];
#pragma unroll
  for (int n = 0; n < DSTATE; ++n) { P[n] = 1.f; q[n] = 0.f; }

  for (int i = 0; i < CL; ++i) {
    const size_t bl = bL + l0 + i;
    float dv = delta[bl * DINNER + d];
    float dx = dv * xc[bl * DINNER + d];
#pragma unroll
    for (int n = 0; n < DSTATE; ++n) {
      float dA = __expf(dv * An[n]);
      P[n] *= dA;
      q[n] = fmaf(dA, q[n], dx * bs[i][n]);
    }
  }
  const size_t base = (((size_t)b * NC + c) * DSTATE) * DINNER + d;
#pragma unroll
  for (int n = 0; n < DSTATE; ++n) {
    Pbuf[base + (size_t)n * DINNER] = P[n];
    Qbuf[base + (size_t)n * DINNER] = q[n];
  }
}

// ---------------------------------------------------------------------------
// Combine: per (b, d, n) serial over the NC chunks; writes each chunk's
// initial state. 65536 threads, fully independent.
// ---------------------------------------------------------------------------
__launch_bounds__(256)
__global__ void scan_combine(const float* __restrict__ Pbuf,
                             const float* __restrict__ Qbuf,
                             float* __restrict__ Hini)
{
  const int idx = blockIdx.x * 256 + threadIdx.x;   // [0, 65536)
  const int d = idx & (DINNER - 1);
  const int n = (idx >> 11) & (DSTATE - 1);
  const int b = idx >> 15;

  float h = 0.f;
#pragma unroll
  for (int c = 0; c < NC; ++c) {
    const size_t off = (((size_t)b * NC + c) * DSTATE + n) * DINNER + d;
    Hini[off] = h;
    h = fmaf(Pbuf[off], h, Qbuf[off]);
  }
}

// ---------------------------------------------------------------------------
// Chunked scan pass 2: re-scan each chunk from Hini, emit gated output
// yg = (y + xc*D) * silu(res).
// ---------------------------------------------------------------------------
__launch_bounds__(256)
__global__ void scan_pass2(const float* __restrict__ delta,
                           const float* __restrict__ xc,
                           const float* __restrict__ xz,
                           const float* __restrict__ xdbl,
                           const float* __restrict__ A_log,
                           const float* __restrict__ Dvec,
                           const float* __restrict__ Hini,
                           float* __restrict__ yg)
{
  const int blk = blockIdx.x;
  const int b = blk >> 7;
  const int c = (blk >> 3) & (NC - 1);
  const int d = ((blk & 7) << 8) + threadIdx.x;

  float An[DSTATE];
#pragma unroll
  for (int n = 0; n < DSTATE; ++n) An[n] = -__expf(A_log[d * DSTATE + n]);
  const float Dd = Dvec[d];

  float h[DSTATE];
  const size_t base = (((size_t)b * NC + c) * DSTATE) * DINNER + d;
#pragma unroll
  for (int n = 0; n < DSTATE; ++n) h[n] = Hini[base + (size_t)n * DINNER];

  __shared__ float bc[CL][2 * DSTATE];   // B | C rows for this chunk (16 KiB)
  const size_t bL = (size_t)b * L_;
  const int l0 = c * CL;
  for (int j = threadIdx.x; j < CL * 8; j += 256) {
    int step = j >> 3, q = j & 7;
    *(float4*)&bc[step][q * 4] =
        *(const float4*)&xdbl[(bL + l0 + step) * 96 + DTRANK + q * 4];
  }
  __syncthreads();

  for (int i = 0; i < CL; ++i) {
    const size_t bl = bL + l0 + i;
    float dv = delta[bl * DINNER + d];
    float xv = xc[bl * DINNER + d];
    float rv = xz[bl * (2 * DINNER) + DINNER + d];
    float dx = dv * xv;
    float y = 0.f;
#pragma unroll
    for (int n = 0; n < DSTATE; ++n) {
      float dA = __expf(dv * An[n]);
      h[n] = fmaf(dA, h[n], dx * bc[i][n]);
      y = fmaf(h[n], bc[i][DSTATE + n], y);
    }
    yg[bl * DINNER + d] = (y + xv * Dd) * (rv * sigmoidf_(rv));
  }
}

// ---------------------------------------------------------------------------
extern "C" void kernel_launch(void* const* d_in, const int* in_sizes, int n_in,
                              void* d_out, int out_size, void* d_ws,
                              size_t ws_size, hipStream_t stream)
{
  const float* x      = (const float*)d_in[0];
  const float* W_in   = (const float*)d_in[1];
  const float* conv_w = (const float*)d_in[2];
  const float* conv_b = (const float*)d_in[3];
  const float* W_x    = (const float*)d_in[4];
  const float* W_dt   = (const float*)d_in[5];
  const float* b_dt   = (const float*)d_in[6];
  const float* A_log  = (const float*)d_in[7];
  const float* Dv     = (const float*)d_in[8];
  const float* W_out  = (const float*)d_in[9];
  float* out = (float*)d_out;

  float* ws = (float*)d_ws;
  float* xz    = ws;                                   // 16,777,216 f
  float* xc    = xz    + (size_t)4096 * 4096;          //  8,388,608 f
  float* xdbl  = xc    + (size_t)4096 * 2048;          //    393,216 f
  float* delta = xdbl  + (size_t)4096 * 96;            //  8,388,608 f
  float* yg    = delta + (size_t)4096 * 2048;          //  8,388,608 f
  float* Pbuf  = yg    + (size_t)4096 * 2048;          //  1,048,576 f
  float* Qbuf  = Pbuf  + (size_t)B_ * NC * DSTATE * DINNER;
  float* Hini  = Qbuf  + (size_t)B_ * NC * DSTATE * DINNER;

  const int M = B_ * L_;  // 4096

  // 1) xz = x @ W_in   [4096,1024] x [1024,4096]   (10 args)
  gemm_f32<128, 128, 16, 2, 2, 0>
      <<<dim3((2 * DINNER) / 128, M / 128), 256, 0, stream>>>(
          x, DMODEL, W_in, 2 * DINNER, xz, 2 * DINNER,
          M, 2 * DINNER, DMODEL, nullptr);

  // 2) xc = silu(conv(xi) + conv_b)
  conv_silu<<<4096, 256, 0, stream>>>(xz, conv_w, conv_b, xc);

  // 3) xdbl = xc @ W_x   [4096,2048] x [2048,96]   (10 args)
  gemm_f32<64, 64, 16, 1, 1, 0><<<dim3(2, M / 64), 256, 0, stream>>>(
      xc, DINNER, W_x, 96, xdbl, 96, M, 96, DINNER, nullptr);

  // 4) delta = softplus(xdbl[:,0:64] @ W_dt + b_dt)   (10 args)
  gemm_f32<128, 128, 16, 2, 2, 1>
      <<<dim3(DINNER / 128, M / 128), 256, 0, stream>>>(
          xdbl, 96, W_dt, DINNER, delta, DINNER, M, DINNER, DTRANK, b_dt);

  // 5) chunked selective scan + gating -> yg
  scan_pass1<<<B_ * NC * (DINNER / 256), 256, 0, stream>>>(
      delta, xc, xdbl, A_log, Pbuf, Qbuf);
  scan_combine<<<(B_ * DSTATE * DINNER) / 256, 256, 0, stream>>>(
      Pbuf, Qbuf, Hini);
  scan_pass2<<<B_ * NC * (DINNER / 256), 256, 0, stream>>>(
      delta, xc, xz, xdbl, A_log, Dv, Hini, yg);

  // 6) out = yg @ W_out   [4096,2048] x [2048,1024]
  //    A=yg lda=DINNER | B=W_out ldb=DMODEL | C=out ldc=DMODEL
  //    M=4096  N=DMODEL  K=DINNER  bias=nullptr   -> 10 args
  gemm_f32<128, 128, 16, 2, 2, 0>
      <<<dim3(DMODEL / 128, M / 128), 256, 0, stream>>>(
          yg, DINNER, W_out, DMODEL, out, DMODEL,
          M, DMODEL, DINNER, nullptr);
}

// Round 9
// 759.110 us; speedup vs baseline: 1.7016x; 1.7016x over previous
//
#include <hip/hip_runtime.h>
#include <hip/hip_bf16.h>
#include <cstdint>

// Mamba block fwd, B=2 L=2048 d_model=1024 d_inner=2048 n=16 dt_rank=64 d_conv=4
// Round 9: resubmit (acquisition timeouts r6/r7/r8; file never ran). GEMM1
// (x@W_in) and GEMM6 (yg@W_out) on bf16 MFMA via 3-term split (Markidis):
// A'[m][3k]=(hi,lo,hi), B't[n][3k]=(hi,hi,lo) so a plain bf16 GEMM over
// K'=3K computes hi*hi + lo*hi + hi*lo (err ~2^-17 per product).
// m97 structure: 128x128 tile, BK=64, global_load_lds(16B), 16x16x32 MFMA,
// T2 XOR-swizzle rule-#21-style: linear LDS dest + inverse-swizzled GLOBAL
// source + swizzled ds_read (involution c16 ^= row&7).
//
// Workspace (float units), peak 169.5 MiB (<= proven 173.5):
//   xi   @0          [4096][2048] f32   (GEMM1 cols <2048)  dead after conv
//   res  @8388608    [4096][2048] f32   (GEMM1 cols >=2048) till pass2
//   xc   @16777216   [4096][2048] f32                       till pass2
//   xdbl @25165824   [4096][96]  f32                        till pass2
//   P    @25559040, Q @26607616, Hini @27656192  (1M f each)
//   yg3  @28704768   [4096][6144] bf16 (48 MiB)             till GEMM6
//   bt3_wout @41287680 [1024][6144] bf16 (12 MiB)           till GEMM6
//   aliases (live only until GEMM1): a3_x @16777216 (xc region),
//   bt3_win @23068672 (xc tail + xdbl/P/Q/Hini/yg3-head, all written later)
//   delta reuses xi @0 (written by GEMM4 after conv consumed xi)

#define B_    2
#define L_    2048
#define DMODEL 1024
#define DINNER 2048
#define DSTATE 16
#define DTRANK 64
#define NC    16
#define CL    128

typedef short bf16x8 __attribute__((ext_vector_type(8)));
typedef float f32x4  __attribute__((ext_vector_type(4)));

__device__ __forceinline__ float sigmoidf_(float x) {
  return 1.f / (1.f + __expf(-x));
}
__device__ __forceinline__ float softplusf_(float x) {
  return fmaxf(x, 0.f) + log1pf(__expf(-fabsf(x)));
}
__device__ __forceinline__ unsigned short f2bf_rne(float x) {
  union { float f; unsigned int u; } v; v.f = x;
  unsigned int r = v.u + 0x7FFFu + ((v.u >> 16) & 1u);
  return (unsigned short)(r >> 16);
}
__device__ __forceinline__ float bf2f(unsigned short h) {
  union { float f; unsigned int u; } v; v.u = ((unsigned int)h) << 16;
  return v.f;
}
// A-pattern triplet (hi, lo, hi)
__device__ __forceinline__ void split3_a(float x, unsigned short* o) {
  unsigned short hi = f2bf_rne(x);
  unsigned short lo = f2bf_rne(x - bf2f(hi));
  o[0] = hi; o[1] = lo; o[2] = hi;
}
// B-pattern triplet (hi, hi, lo)
__device__ __forceinline__ void split3_b(float x, unsigned short* o) {
  unsigned short hi = f2bf_rne(x);
  unsigned short lo = f2bf_rne(x - bf2f(hi));
  o[0] = hi; o[1] = hi; o[2] = lo;
}

__device__ __forceinline__ void gload16(const void* g, void* l) {
  __builtin_amdgcn_global_load_lds(
      (const __attribute__((address_space(1))) void*)g,
      (__attribute__((address_space(3))) void*)l, 16, 0, 0);
}

// ---------------------------------------------------------------------------
// bf16 MFMA GEMM, m97-style. C[M,N] = A3[M,K3] * B3t[N,K3]^T (both row-major
// along K3). 128x128 tile, BK=64, 4 waves in 2x2, per-wave 64x64 via 4x4
// 16x16x32 MFMA frags. Swizzle invariant: LDS chunk phys[row][c] holds global
// chunk (row, c ^ (row&7)); staging pre-swizzles the global source col,
// reads XOR the column. SPLITCOL>0: cols<SPLITCOL -> outA, rest -> outB.
// ---------------------------------------------------------------------------
template<int SPLITCOL>
__launch_bounds__(256)
__global__ void gemm_mfma_bf16(const unsigned short* __restrict__ A3,
                               const unsigned short* __restrict__ B3t,
                               float* __restrict__ outA,
                               float* __restrict__ outB,
                               int N, int K3)
{
  __shared__ unsigned short As[128 * 64];
  __shared__ unsigned short Bs[128 * 64];

  const int tid  = threadIdx.x;
  const int lane = tid & 63;
  const int wid  = tid >> 6;
  const int wr   = wid >> 1;
  const int wc   = wid & 1;
  const int m0   = blockIdx.y * 128;
  const int n0   = blockIdx.x * 128;

  // staging geometry: issue covers 8 rows; lane l -> row +l>>3, 16B chunk l&7.
  // source col pre-swizzled: chunk (l&7)^(l>>3) of that row.
  const int srow = lane >> 3;
  const int scol = ((lane & 7) ^ srow) * 8;   // bf16 elements

  const unsigned short* gA = A3 + (size_t)(m0 + wid * 8 + srow) * K3 + scol;
  const unsigned short* gB = B3t + (size_t)(n0 + wid * 8 + srow) * K3 + scol;
  const size_t rs32 = (size_t)32 * K3;

  unsigned short* lA = &As[wid * 8 * 64];
  unsigned short* lB = &Bs[wid * 8 * 64];

  f32x4 acc[4][4];
#pragma unroll
  for (int i = 0; i < 4; ++i)
#pragma unroll
    for (int j = 0; j < 4; ++j) acc[i][j] = (f32x4){0.f, 0.f, 0.f, 0.f};

  const int KT = K3 >> 6;
  for (int kt = 0; kt < KT; ++kt) {
    const int k0 = kt << 6;
#pragma unroll
    for (int i = 0; i < 4; ++i) {
      gload16(gA + i * rs32 + k0, lA + i * 32 * 64);
      gload16(gB + i * rs32 + k0, lB + i * 32 * 64);
    }
    __syncthreads();   // drains vmcnt before use (compiler-inserted waitcnt)

#pragma unroll
    for (int kk = 0; kk < 2; ++kk) {
      const int c16 = kk * 4 + (lane >> 4);   // 16B-chunk index 0..7
      bf16x8 a[4], b[4];
#pragma unroll
      for (int rb = 0; rb < 4; ++rb) {
        const int row = wr * 64 + rb * 16 + (lane & 15);
        a[rb] = *(const bf16x8*)&As[row * 64 + ((c16 ^ (row & 7)) << 3)];
        const int col = wc * 64 + rb * 16 + (lane & 15);
        b[rb] = *(const bf16x8*)&Bs[col * 64 + ((c16 ^ (col & 7)) << 3)];
      }
#pragma unroll
      for (int rb = 0; rb < 4; ++rb)
#pragma unroll
        for (int nb = 0; nb < 4; ++nb)
          acc[rb][nb] = __builtin_amdgcn_mfma_f32_16x16x32_bf16(
              a[rb], b[nb], acc[rb][nb], 0, 0, 0);
    }
    __syncthreads();
  }

  // epilogue: C/D frag layout col=lane&15, row=(lane>>4)*4+j  [m89-verified]
  const int crow0 = (lane >> 4) * 4;
  const int ccol  = lane & 15;
#pragma unroll
  for (int rb = 0; rb < 4; ++rb) {
#pragma unroll
    for (int nb = 0; nb < 4; ++nb) {
      const int gc = n0 + wc * 64 + nb * 16 + ccol;
#pragma unroll
      for (int j = 0; j < 4; ++j) {
        const int gr = m0 + wr * 64 + rb * 16 + crow0 + j;
        const float v = acc[rb][nb][j];
        if (SPLITCOL > 0) {
          if (gc < SPLITCOL) outA[(size_t)gr * SPLITCOL + gc] = v;
          else               outB[(size_t)gr * SPLITCOL + (gc - SPLITCOL)] = v;
        } else {
          outA[(size_t)gr * N + gc] = v;
        }
      }
    }
  }
}

// ---------------------------------------------------------------------------
// x [4096][1024] f32 -> a3_x [4096][3072] bf16 (hi,lo,hi). 4096x256 threads,
// one float4 (4 k) -> 12 bf16 per thread.
// ---------------------------------------------------------------------------
__launch_bounds__(256)
__global__ void split_a3(const float* __restrict__ in,
                         unsigned short* __restrict__ out)
{
  const int idx = blockIdx.x * 256 + threadIdx.x;  // [0, 4096*256)
  const int row = idx >> 8;
  const int q   = idx & 255;
  float4 v = *(const float4*)&in[(size_t)row * DMODEL + q * 4];
  unsigned short buf[12] __attribute__((aligned(8)));
  split3_a(v.x, &buf[0]);
  split3_a(v.y, &buf[3]);
  split3_a(v.z, &buf[6]);
  split3_a(v.w, &buf[9]);
  unsigned short* o = out + (size_t)row * 3072 + q * 12;
#pragma unroll
  for (int j = 0; j < 3; ++j)
    *(ushort4*)&o[j * 4] = *(const ushort4*)&buf[j * 4];
}

// ---------------------------------------------------------------------------
// B [K][N] f32 -> out [N][3K] bf16 (hi,hi,lo), transposed via LDS 64x64 tile.
// grid (N/64, K/64), 256 threads.
// ---------------------------------------------------------------------------
__launch_bounds__(256)
__global__ void split_bt3(const float* __restrict__ B,
                          unsigned short* __restrict__ out,
                          int K, int N)
{
  __shared__ float T[64][65];
  const int n0 = blockIdx.x * 64;
  const int k0 = blockIdx.y * 64;
  const int t  = threadIdx.x;

  const int nl4 = (t & 15) * 4;
  const int klr = t >> 4;
#pragma unroll
  for (int i = 0; i < 4; ++i) {
    float4 v = *(const float4*)&B[(size_t)(k0 + klr + i * 16) * N + n0 + nl4];
    T[klr + i * 16][nl4 + 0] = v.x;
    T[klr + i * 16][nl4 + 1] = v.y;
    T[klr + i * 16][nl4 + 2] = v.z;
    T[klr + i * 16][nl4 + 3] = v.w;
  }
  __syncthreads();

  const int nl = t >> 2;
  const int kc = (t & 3) * 16;
  unsigned short buf[48] __attribute__((aligned(8)));
#pragma unroll
  for (int kk = 0; kk < 16; ++kk) split3_b(T[kc + kk][nl], &buf[kk * 3]);
  unsigned short* o = out + (size_t)(n0 + nl) * (3 * K) + 3 * (k0 + kc);
#pragma unroll
  for (int j = 0; j < 12; ++j)
    *(ushort4*)&o[j * 4] = *(const ushort4*)&buf[j * 4];
}

// ---------------------------------------------------------------------------
// fp32 tiled GEMM (kept for GEMM3/GEMM4). EPI: 0 none, 1 softplus(acc+bias).
// ---------------------------------------------------------------------------
template<int BM, int BN, int BK, int RG, int CG, int EPI>
__launch_bounds__(256)
__global__ void gemm_f32(const float* __restrict__ A, int lda,
                         const float* __restrict__ B, int ldb,
                         float* __restrict__ C, int ldc,
                         int M, int N, int K,
                         const float* __restrict__ bias)
{
  __shared__ float As[BK][BM + 4];
  __shared__ float Bs[BK][BN + 4];

  const int tid = threadIdx.x;
  const int tx = tid & 15;
  const int ty = tid >> 4;
  const int m0 = blockIdx.y * BM;
  const int n0 = blockIdx.x * BN;

  float acc[RG * 4][CG * 4];
#pragma unroll
  for (int i = 0; i < RG * 4; ++i)
#pragma unroll
    for (int j = 0; j < CG * 4; ++j) acc[i][j] = 0.f;

  const int KF4 = BK / 4;
  const int NF4 = BN / 4;

  for (int k0 = 0; k0 < K; k0 += BK) {
#pragma unroll
    for (int j = tid; j < BM * KF4; j += 256) {
      int row = j / KF4, kq = j % KF4;
      float4 v = *(const float4*)&A[(size_t)(m0 + row) * lda + k0 + kq * 4];
      As[kq * 4 + 0][row] = v.x;
      As[kq * 4 + 1][row] = v.y;
      As[kq * 4 + 2][row] = v.z;
      As[kq * 4 + 3][row] = v.w;
    }
#pragma unroll
    for (int j = tid; j < BK * NF4; j += 256) {
      int row = j / NF4, nq = j % NF4;
      int c = n0 + nq * 4;
      float4 v;
      if (c + 3 < N) {
        v = *(const float4*)&B[(size_t)(k0 + row) * ldb + c];
      } else {
        const float* bp = &B[(size_t)(k0 + row) * ldb];
        v.x = (c + 0 < N) ? bp[c + 0] : 0.f;
        v.y = (c + 1 < N) ? bp[c + 1] : 0.f;
        v.z = (c + 2 < N) ? bp[c + 2] : 0.f;
        v.w = (c + 3 < N) ? bp[c + 3] : 0.f;
      }
      *(float4*)&Bs[row][nq * 4] = v;
    }
    __syncthreads();

#pragma unroll
    for (int k = 0; k < BK; ++k) {
      float a[RG][4], b[CG][4];
#pragma unroll
      for (int g = 0; g < RG; ++g) {
        float4 va = *(const float4*)&As[k][g * (BM / RG) + ty * 4];
        a[g][0] = va.x; a[g][1] = va.y; a[g][2] = va.z; a[g][3] = va.w;
      }
#pragma unroll
      for (int h = 0; h < CG; ++h) {
        float4 vb = *(const float4*)&Bs[k][h * (BN / CG) + tx * 4];
        b[h][0] = vb.x; b[h][1] = vb.y; b[h][2] = vb.z; b[h][3] = vb.w;
      }
#pragma unroll
      for (int g = 0; g < RG; ++g)
#pragma unroll
        for (int i = 0; i < 4; ++i)
#pragma unroll
          for (int h = 0; h < CG; ++h)
#pragma unroll
            for (int j = 0; j < 4; ++j)
              acc[g * 4 + i][h * 4 + j] =
                  fmaf(a[g][i], b[h][j], acc[g * 4 + i][h * 4 + j]);
    }
    __syncthreads();
  }

#pragma unroll
  for (int g = 0; g < RG; ++g) {
#pragma unroll
    for (int i = 0; i < 4; ++i) {
      int r = m0 + g * (BM / RG) + ty * 4 + i;
#pragma unroll
      for (int h = 0; h < CG; ++h) {
        int c = n0 + h * (BN / CG) + tx * 4;
        float4 v;
        v.x = acc[g * 4 + i][h * 4 + 0];
        v.y = acc[g * 4 + i][h * 4 + 1];
        v.z = acc[g * 4 + i][h * 4 + 2];
        v.w = acc[g * 4 + i][h * 4 + 3];
        if (c + 3 < N) {
          if (EPI == 1) {
            v.x = softplusf_(v.x + bias[c + 0]);
            v.y = softplusf_(v.y + bias[c + 1]);
            v.z = softplusf_(v.z + bias[c + 2]);
            v.w = softplusf_(v.w + bias[c + 3]);
          }
          *(float4*)&C[(size_t)r * ldc + c] = v;
        } else {
          float vv[4] = {v.x, v.y, v.z, v.w};
#pragma unroll
          for (int j = 0; j < 4; ++j)
            if (c + j < N) {
              float o = vv[j];
              if (EPI == 1) o = softplusf_(o + bias[c + j]);
              C[(size_t)r * ldc + c + j] = o;
            }
        }
      }
    }
  }
}

// ---------------------------------------------------------------------------
// Causal depthwise conv1d (k=4, left-pad 3) + bias + SiLU. xi [4096][2048].
// ---------------------------------------------------------------------------
__launch_bounds__(256)
__global__ void conv_silu(const float* __restrict__ xi,
                          const float* __restrict__ conv_w,
                          const float* __restrict__ conv_b,
                          float* __restrict__ xc)
{
  const int total = B_ * L_ * (DINNER / 4);
  for (int idx = blockIdx.x * blockDim.x + threadIdx.x; idx < total;
       idx += gridDim.x * blockDim.x) {
    int d4 = idx & (DINNER / 4 - 1);
    int l = (idx >> 9) & (L_ - 1);
    int b = idx >> 20;
    int d = d4 * 4;

    float w[4][4];
#pragma unroll
    for (int c = 0; c < 4; ++c) {
      float4 wv = *(const float4*)&conv_w[(d + c) * 4];
      w[c][0] = wv.x; w[c][1] = wv.y; w[c][2] = wv.z; w[c][3] = wv.w;
    }
    float4 bv = *(const float4*)&conv_b[d];
    float s[4] = {bv.x, bv.y, bv.z, bv.w};
#pragma unroll
    for (int t = 0; t < 4; ++t) {
      int ls = l - 3 + t;
      if (ls >= 0) {
        float4 xv = *(const float4*)&xi[(size_t)(b * L_ + ls) * DINNER + d];
        s[0] = fmaf(w[0][t], xv.x, s[0]);
        s[1] = fmaf(w[1][t], xv.y, s[1]);
        s[2] = fmaf(w[2][t], xv.z, s[2]);
        s[3] = fmaf(w[3][t], xv.w, s[3]);
      }
    }
    float4 o;
    o.x = s[0] * sigmoidf_(s[0]);
    o.y = s[1] * sigmoidf_(s[1]);
    o.z = s[2] * sigmoidf_(s[2]);
    o.w = s[3] * sigmoidf_(s[3]);
    *(float4*)&xc[(size_t)idx * 4] = o;
  }
}

// ---------------------------------------------------------------------------
// Chunked scan pass 1.
// ---------------------------------------------------------------------------
__launch_bounds__(256)
__global__ void scan_pass1(const float* __restrict__ delta,
                           const float* __restrict__ xc,
                           const float* __restrict__ xdbl,
                           const float* __restrict__ A_log,
                           float* __restrict__ Pbuf,
                           float* __restrict__ Qbuf)
{
  const int blk = blockIdx.x;
  const int b = blk >> 7;
  const int c = (blk >> 3) & (NC - 1);
  const int d = ((blk & 7) << 8) + threadIdx.x;

  float An[DSTATE];
#pragma unroll
  for (int n = 0; n < DSTATE; ++n) An[n] = -__expf(A_log[d * DSTATE + n]);

  __shared__ float bs[CL][DSTATE];
  const size_t bL = (size_t)b * L_;
  const int l0 = c * CL;
  for (int j = threadIdx.x; j < CL * 4; j += 256) {
    int step = j >> 2, q = j & 3;
    *(float4*)&bs[step][q * 4] =
        *(const float4*)&xdbl[(bL + l0 + step) * 96 + DTRANK + q * 4];
  }
  __syncthreads();

  float P[DSTATE], q[DSTATE];
#pragma unroll
  for (int n = 0; n < DSTATE; ++n) { P[n] = 1.f; q[n] = 0.f; }

  for (int i = 0; i < CL; ++i) {
    const size_t bl = bL + l0 + i;
    float dv = delta[bl * DINNER + d];
    float dx = dv * xc[bl * DINNER + d];
#pragma unroll
    for (int n = 0; n < DSTATE; ++n) {
      float dA = __expf(dv * An[n]);
      P[n] *= dA;
      q[n] = fmaf(dA, q[n], dx * bs[i][n]);
    }
  }
  const size_t base = (((size_t)b * NC + c) * DSTATE) * DINNER + d;
#pragma unroll
  for (int n = 0; n < DSTATE; ++n) {
    Pbuf[base + (size_t)n * DINNER] = P[n];
    Qbuf[base + (size_t)n * DINNER] = q[n];
  }
}

__launch_bounds__(256)
__global__ void scan_combine(const float* __restrict__ Pbuf,
                             const float* __restrict__ Qbuf,
                             float* __restrict__ Hini)
{
  const int idx = blockIdx.x * 256 + threadIdx.x;
  const int d = idx & (DINNER - 1);
  const int n = (idx >> 11) & (DSTATE - 1);
  const int b = idx >> 15;

  float h = 0.f;
#pragma unroll
  for (int c = 0; c < NC; ++c) {
    const size_t off = (((size_t)b * NC + c) * DSTATE + n) * DINNER + d;
    Hini[off] = h;
    h = fmaf(Pbuf[off], h, Qbuf[off]);
  }
}

// ---------------------------------------------------------------------------
// Chunked scan pass 2: re-scan from Hini, gate, emit yg as (hi,lo,hi) bf16
// triplets -> yg3 [4096][6144] (A-operand of GEMM6, 3-term split layout).
// ---------------------------------------------------------------------------
__launch_bounds__(256)
__global__ void scan_pass2(const float* __restrict__ delta,
                           const float* __restrict__ xc,
                           const float* __restrict__ res,
                           const float* __restrict__ xdbl,
                           const float* __restrict__ A_log,
                           const float* __restrict__ Dvec,
                           const float* __restrict__ Hini,
                           unsigned short* __restrict__ yg3)
{
  const int blk = blockIdx.x;
  const int b = blk >> 7;
  const int c = (blk >> 3) & (NC - 1);
  const int d = ((blk & 7) << 8) + threadIdx.x;

  float An[DSTATE];
#pragma unroll
  for (int n = 0; n < DSTATE; ++n) An[n] = -__expf(A_log[d * DSTATE + n]);
  const float Dd = Dvec[d];

  float h[DSTATE];
  const size_t base = (((size_t)b * NC + c) * DSTATE) * DINNER + d;
#pragma unroll
  for (int n = 0; n < DSTATE; ++n) h[n] = Hini[base + (size_t)n * DINNER];

  __shared__ float bc[CL][2 * DSTATE];
  const size_t bL = (size_t)b * L_;
  const int l0 = c * CL;
  for (int j = threadIdx.x; j < CL * 8; j += 256) {
    int step = j >> 3, q = j & 7;
    *(float4*)&bc[step][q * 4] =
        *(const float4*)&xdbl[(bL + l0 + step) * 96 + DTRANK + q * 4];
  }
  __syncthreads();

  for (int i = 0; i < CL; ++i) {
    const size_t bl = bL + l0 + i;
    float dv = delta[bl * DINNER + d];
    float xv = xc[bl * DINNER + d];
    float rv = res[bl * DINNER + d];
    float dx = dv * xv;
    float y = 0.f;
#pragma unroll
    for (int n = 0; n < DSTATE; ++n) {
      float dA = __expf(dv * An[n]);
      h[n] = fmaf(dA, h[n], dx * bc[i][n]);
      y = fmaf(h[n], bc[i][DSTATE + n], y);
    }
    float v = (y + xv * Dd) * (rv * sigmoidf_(rv));
    unsigned short hi = f2bf_rne(v);
    unsigned short lo = f2bf_rne(v - bf2f(hi));
    const size_t o = bl * 6144 + 3 * (size_t)d;
    yg3[o + 0] = hi; yg3[o + 1] = lo; yg3[o + 2] = hi;
  }
}

// ---------------------------------------------------------------------------
extern "C" void kernel_launch(void* const* d_in, const int* in_sizes, int n_in,
                              void* d_out, int out_size, void* d_ws,
                              size_t ws_size, hipStream_t stream)
{
  const float* x      = (const float*)d_in[0];
  const float* W_in   = (const float*)d_in[1];
  const float* conv_w = (const float*)d_in[2];
  const float* conv_b = (const float*)d_in[3];
  const float* W_x    = (const float*)d_in[4];
  const float* W_dt   = (const float*)d_in[5];
  const float* b_dt   = (const float*)d_in[6];
  const float* A_log  = (const float*)d_in[7];
  const float* Dv     = (const float*)d_in[8];
  const float* W_out  = (const float*)d_in[9];
  float* out = (float*)d_out;

  float* ws = (float*)d_ws;
  float* xi    = ws;                    // 8,388,608 f
  float* res   = ws + 8388608;          // 8,388,608 f
  float* xc    = ws + 16777216;         // 8,388,608 f
  float* xdbl  = ws + 25165824;         //   393,216 f
  float* Pbuf  = ws + 25559040;         // 1,048,576 f
  float* Qbuf  = ws + 26607616;         // 1,048,576 f
  float* Hini  = ws + 27656192;         // 1,048,576 f
  unsigned short* yg3      = (unsigned short*)(ws + 28704768);  // 4096*6144 us
  unsigned short* bt3_wout = (unsigned short*)(ws + 41287680);  // 1024*6144 us
  // aliases, live only until GEMM1 completes:
  unsigned short* a3_x     = (unsigned short*)(ws + 16777216);  // 4096*3072 us
  unsigned short* bt3_win  = (unsigned short*)(ws + 23068672);  // 4096*3072 us
  float* delta = ws;                    // reuses xi region after conv

  const int M = B_ * L_;  // 4096

  // 1) split x and W_in into 3-term bf16
  split_a3<<<4096, 256, 0, stream>>>(x, a3_x);
  split_bt3<<<dim3(4096 / 64, 1024 / 64), 256, 0, stream>>>(W_in, bt3_win,
                                                            1024, 4096);

  // 2) GEMM1 (MFMA): [4096,3072]x[3072,4096] -> xi (cols<2048) | res (rest)
  gemm_mfma_bf16<2048><<<dim3(32, 32), 256, 0, stream>>>(
      a3_x, bt3_win, xi, res, 4096, 3072);

  // 3) split W_out (for GEMM6 later; dedicated region)
  split_bt3<<<dim3(1024 / 64, 2048 / 64), 256, 0, stream>>>(W_out, bt3_wout,
                                                            2048, 1024);

  // 4) xc = silu(conv(xi) + conv_b)   (overwrites a3_x region)
  conv_silu<<<4096, 256, 0, stream>>>(xi, conv_w, conv_b, xc);

  // 5) xdbl = xc @ W_x   [4096,2048]x[2048,96]
  gemm_f32<64, 64, 16, 1, 1, 0><<<dim3(2, M / 64), 256, 0, stream>>>(
      xc, DINNER, W_x, 96, xdbl, 96, M, 96, DINNER, nullptr);

  // 6) delta = softplus(xdbl[:,0:64] @ W_dt + b_dt)  (writes into xi region)
  gemm_f32<128, 128, 16, 2, 2, 1>
      <<<dim3(DINNER / 128, M / 128), 256, 0, stream>>>(
          xdbl, 96, W_dt, DINNER, delta, DINNER, M, DINNER, DTRANK, b_dt);

  // 7) chunked selective scan + gating -> yg3 (3-term bf16 triplets)
  scan_pass1<<<B_ * NC * (DINNER / 256), 256, 0, stream>>>(
      delta, xc, xdbl, A_log, Pbuf, Qbuf);
  scan_combine<<<(B_ * DSTATE * DINNER) / 256, 256, 0, stream>>>(
      Pbuf, Qbuf, Hini);
  scan_pass2<<<B_ * NC * (DINNER / 256), 256, 0, stream>>>(
      delta, xc, res, xdbl, A_log, Dv, Hini, yg3);

  // 8) GEMM6 (MFMA): [4096,6144]x[6144,1024] -> out
  gemm_mfma_bf16<0><<<dim3(8, 32), 256, 0, stream>>>(
      yg3, bt3_wout, out, nullptr, 1024, 6144);
}

// Round 10
// 703.535 us; speedup vs baseline: 1.8360x; 1.0790x over previous
//
#include <hip/hip_runtime.h>
#include <hip/hip_bf16.h>
#include <cstdint>

// Mamba block fwd, B=2 L=2048 d_model=1024 d_inner=2048 n=16 dt_rank=64 d_conv=4
// Round 10: replace GEMM3 (xc@W_x, was 160us latency-bound: 128 WGs, occupancy
// 5.8%, VALUBusy 8.9%) with split-K LDS-free tall-skinny kernel (1024 blocks,
// partials in dead xi region) + float4 reduce. MFMA GEMMs 1/6 unchanged
// (r9: passed, absmax 0.03125, 759us total).
//
// Workspace (float units), peak 169.5 MiB:
//   xi   @0          [4096][2048] f32  dead after conv; GEMM3 partials live
//                    here between conv and reduce; delta (GEMM4 out) after
//   res  @8388608    [4096][2048] f32   till pass2
//   xc   @16777216   [4096][2048] f32   till pass2
//   xdbl @25165824   [4096][96]  f32    till pass2
//   P    @25559040, Q @26607616, Hini @27656192  (1M f each)
//   yg3  @28704768   [4096][6144] bf16 (48 MiB)  till GEMM6
//   bt3_wout @41287680 [1024][6144] bf16 (12 MiB) till GEMM6
//   aliases (live only until GEMM1): a3_x @16777216, bt3_win @23068672

#define B_    2
#define L_    2048
#define DMODEL 1024
#define DINNER 2048
#define DSTATE 16
#define DTRANK 64
#define NC    16
#define CL    128

typedef short bf16x8 __attribute__((ext_vector_type(8)));
typedef float f32x4  __attribute__((ext_vector_type(4)));

__device__ __forceinline__ float sigmoidf_(float x) {
  return 1.f / (1.f + __expf(-x));
}
__device__ __forceinline__ float softplusf_(float x) {
  return fmaxf(x, 0.f) + log1pf(__expf(-fabsf(x)));
}
__device__ __forceinline__ unsigned short f2bf_rne(float x) {
  union { float f; unsigned int u; } v; v.f = x;
  unsigned int r = v.u + 0x7FFFu + ((v.u >> 16) & 1u);
  return (unsigned short)(r >> 16);
}
__device__ __forceinline__ float bf2f(unsigned short h) {
  union { float f; unsigned int u; } v; v.u = ((unsigned int)h) << 16;
  return v.f;
}
__device__ __forceinline__ void split3_a(float x, unsigned short* o) {
  unsigned short hi = f2bf_rne(x);
  unsigned short lo = f2bf_rne(x - bf2f(hi));
  o[0] = hi; o[1] = lo; o[2] = hi;
}
__device__ __forceinline__ void split3_b(float x, unsigned short* o) {
  unsigned short hi = f2bf_rne(x);
  unsigned short lo = f2bf_rne(x - bf2f(hi));
  o[0] = hi; o[1] = hi; o[2] = lo;
}

__device__ __forceinline__ void gload16(const void* g, void* l) {
  __builtin_amdgcn_global_load_lds(
      (const __attribute__((address_space(1))) void*)g,
      (__attribute__((address_space(3))) void*)l, 16, 0, 0);
}

// ---------------------------------------------------------------------------
// bf16 MFMA GEMM, m97-style (unchanged from r9, verified on HW).
// ---------------------------------------------------------------------------
template<int SPLITCOL>
__launch_bounds__(256)
__global__ void gemm_mfma_bf16(const unsigned short* __restrict__ A3,
                               const unsigned short* __restrict__ B3t,
                               float* __restrict__ outA,
                               float* __restrict__ outB,
                               int N, int K3)
{
  __shared__ unsigned short As[128 * 64];
  __shared__ unsigned short Bs[128 * 64];

  const int tid  = threadIdx.x;
  const int lane = tid & 63;
  const int wid  = tid >> 6;
  const int wr   = wid >> 1;
  const int wc   = wid & 1;
  const int m0   = blockIdx.y * 128;
  const int n0   = blockIdx.x * 128;

  const int srow = lane >> 3;
  const int scol = ((lane & 7) ^ srow) * 8;

  const unsigned short* gA = A3 + (size_t)(m0 + wid * 8 + srow) * K3 + scol;
  const unsigned short* gB = B3t + (size_t)(n0 + wid * 8 + srow) * K3 + scol;
  const size_t rs32 = (size_t)32 * K3;

  unsigned short* lA = &As[wid * 8 * 64];
  unsigned short* lB = &Bs[wid * 8 * 64];

  f32x4 acc[4][4];
#pragma unroll
  for (int i = 0; i < 4; ++i)
#pragma unroll
    for (int j = 0; j < 4; ++j) acc[i][j] = (f32x4){0.f, 0.f, 0.f, 0.f};

  const int KT = K3 >> 6;
  for (int kt = 0; kt < KT; ++kt) {
    const int k0 = kt << 6;
#pragma unroll
    for (int i = 0; i < 4; ++i) {
      gload16(gA + i * rs32 + k0, lA + i * 32 * 64);
      gload16(gB + i * rs32 + k0, lB + i * 32 * 64);
    }
    __syncthreads();

#pragma unroll
    for (int kk = 0; kk < 2; ++kk) {
      const int c16 = kk * 4 + (lane >> 4);
      bf16x8 a[4], b[4];
#pragma unroll
      for (int rb = 0; rb < 4; ++rb) {
        const int row = wr * 64 + rb * 16 + (lane & 15);
        a[rb] = *(const bf16x8*)&As[row * 64 + ((c16 ^ (row & 7)) << 3)];
        const int col = wc * 64 + rb * 16 + (lane & 15);
        b[rb] = *(const bf16x8*)&Bs[col * 64 + ((c16 ^ (col & 7)) << 3)];
      }
#pragma unroll
      for (int rb = 0; rb < 4; ++rb)
#pragma unroll
        for (int nb = 0; nb < 4; ++nb)
          acc[rb][nb] = __builtin_amdgcn_mfma_f32_16x16x32_bf16(
              a[rb], b[nb], acc[rb][nb], 0, 0, 0);
    }
    __syncthreads();
  }

  const int crow0 = (lane >> 4) * 4;
  const int ccol  = lane & 15;
#pragma unroll
  for (int rb = 0; rb < 4; ++rb) {
#pragma unroll
    for (int nb = 0; nb < 4; ++nb) {
      const int gc = n0 + wc * 64 + nb * 16 + ccol;
#pragma unroll
      for (int j = 0; j < 4; ++j) {
        const int gr = m0 + wr * 64 + rb * 16 + crow0 + j;
        const float v = acc[rb][nb][j];
        if (SPLITCOL > 0) {
          if (gc < SPLITCOL) outA[(size_t)gr * SPLITCOL + gc] = v;
          else               outB[(size_t)gr * SPLITCOL + (gc - SPLITCOL)] = v;
        } else {
          outA[(size_t)gr * N + gc] = v;
        }
      }
    }
  }
}

// ---------------------------------------------------------------------------
// x [4096][1024] f32 -> a3_x [4096][3072] bf16 (hi,lo,hi).
// ---------------------------------------------------------------------------
__launch_bounds__(256)
__global__ void split_a3(const float* __restrict__ in,
                         unsigned short* __restrict__ out)
{
  const int idx = blockIdx.x * 256 + threadIdx.x;
  const int row = idx >> 8;
  const int q   = idx & 255;
  float4 v = *(const float4*)&in[(size_t)row * DMODEL + q * 4];
  unsigned short buf[12] __attribute__((aligned(8)));
  split3_a(v.x, &buf[0]);
  split3_a(v.y, &buf[3]);
  split3_a(v.z, &buf[6]);
  split3_a(v.w, &buf[9]);
  unsigned short* o = out + (size_t)row * 3072 + q * 12;
#pragma unroll
  for (int j = 0; j < 3; ++j)
    *(ushort4*)&o[j * 4] = *(const ushort4*)&buf[j * 4];
}

// ---------------------------------------------------------------------------
// B [K][N] f32 -> out [N][3K] bf16 (hi,hi,lo), transposed via LDS 64x64 tile.
// ---------------------------------------------------------------------------
__launch_bounds__(256)
__global__ void split_bt3(const float* __restrict__ B,
                          unsigned short* __restrict__ out,
                          int K, int N)
{
  __shared__ float T[64][65];
  const int n0 = blockIdx.x * 64;
  const int k0 = blockIdx.y * 64;
  const int t  = threadIdx.x;

  const int nl4 = (t & 15) * 4;
  const int klr = t >> 4;
#pragma unroll
  for (int i = 0; i < 4; ++i) {
    float4 v = *(const float4*)&B[(size_t)(k0 + klr + i * 16) * N + n0 + nl4];
    T[klr + i * 16][nl4 + 0] = v.x;
    T[klr + i * 16][nl4 + 1] = v.y;
    T[klr + i * 16][nl4 + 2] = v.z;
    T[klr + i * 16][nl4 + 3] = v.w;
  }
  __syncthreads();

  const int nl = t >> 2;
  const int kc = (t & 3) * 16;
  unsigned short buf[48] __attribute__((aligned(8)));
#pragma unroll
  for (int kk = 0; kk < 16; ++kk) split3_b(T[kc + kk][nl], &buf[kk * 3]);
  unsigned short* o = out + (size_t)(n0 + nl) * (3 * K) + 3 * (k0 + kc);
#pragma unroll
  for (int j = 0; j < 12; ++j)
    *(ushort4*)&o[j * 4] = *(const ushort4*)&buf[j * 4];
}

// ---------------------------------------------------------------------------
// GEMM3 replacement: split-K tall-skinny  part[ks][4096][96] =
//   sum_{k in chunk ks} xc[m][k] * W_x[k][96].
// grid (KS=4, 256), 384 thr: r = t/24 (16 rows), cq = t%24 (24 col-quads).
// No LDS; W_x chunk (192KB) L2-resident, A row chunk L1-resident.
// ---------------------------------------------------------------------------
#define KS_   4
#define KCH   (DINNER / KS_)   // 512
__launch_bounds__(384)
__global__ void gemm_wx_splitk(const float* __restrict__ xc,
                               const float* __restrict__ wx,
                               float* __restrict__ part)
{
  const int ks = blockIdx.x;
  const int m0 = blockIdx.y * 16;
  const int t  = threadIdx.x;
  const int r  = t / 24;
  const int c  = (t % 24) * 4;
  const int k0 = ks * KCH;

  const float* arow = xc + (size_t)(m0 + r) * DINNER + k0;
  const float* wp   = wx + (size_t)k0 * 96 + c;

  float ax = 0.f, ay = 0.f, az = 0.f, aw = 0.f;
  for (int k = 0; k < KCH; k += 4) {
    float4 a  = *(const float4*)&arow[k];
    float4 w0 = *(const float4*)&wp[(size_t)(k + 0) * 96];
    float4 w1 = *(const float4*)&wp[(size_t)(k + 1) * 96];
    float4 w2 = *(const float4*)&wp[(size_t)(k + 2) * 96];
    float4 w3 = *(const float4*)&wp[(size_t)(k + 3) * 96];
    ax = fmaf(a.x, w0.x, ax); ax = fmaf(a.y, w1.x, ax);
    ax = fmaf(a.z, w2.x, ax); ax = fmaf(a.w, w3.x, ax);
    ay = fmaf(a.x, w0.y, ay); ay = fmaf(a.y, w1.y, ay);
    ay = fmaf(a.z, w2.y, ay); ay = fmaf(a.w, w3.y, ay);
    az = fmaf(a.x, w0.z, az); az = fmaf(a.y, w1.z, az);
    az = fmaf(a.z, w2.z, az); az = fmaf(a.w, w3.z, az);
    aw = fmaf(a.x, w0.w, aw); aw = fmaf(a.y, w1.w, aw);
    aw = fmaf(a.z, w2.w, aw); aw = fmaf(a.w, w3.w, aw);
  }
  float4 o = {ax, ay, az, aw};
  *(float4*)&part[((size_t)ks * 4096 + m0 + r) * 96 + c] = o;
}

// part[4][4096][96] -> xdbl[4096][96]   (float4 grid-stride, 1 pass)
__launch_bounds__(256)
__global__ void reduce_wx(const float* __restrict__ part,
                          float* __restrict__ xdbl)
{
  const int i = blockIdx.x * 256 + threadIdx.x;   // [0, 98304) float4 idx
  const size_t S = (size_t)4096 * 96 / 4;
  const float4* p = (const float4*)part;
  float4 a = p[i];
  float4 b = p[i + S];
  float4 c = p[i + 2 * S];
  float4 d = p[i + 3 * S];
  float4 o;
  o.x = (a.x + b.x) + (c.x + d.x);
  o.y = (a.y + b.y) + (c.y + d.y);
  o.z = (a.z + b.z) + (c.z + d.z);
  o.w = (a.w + b.w) + (c.w + d.w);
  ((float4*)xdbl)[i] = o;
}

// ---------------------------------------------------------------------------
// fp32 tiled GEMM (kept for GEMM4). EPI: 0 none, 1 softplus(acc+bias).
// ---------------------------------------------------------------------------
template<int BM, int BN, int BK, int RG, int CG, int EPI>
__launch_bounds__(256)
__global__ void gemm_f32(const float* __restrict__ A, int lda,
                         const float* __restrict__ B, int ldb,
                         float* __restrict__ C, int ldc,
                         int M, int N, int K,
                         const float* __restrict__ bias)
{
  __shared__ float As[BK][BM + 4];
  __shared__ float Bs[BK][BN + 4];

  const int tid = threadIdx.x;
  const int tx = tid & 15;
  const int ty = tid >> 4;
  const int m0 = blockIdx.y * BM;
  const int n0 = blockIdx.x * BN;

  float acc[RG * 4][CG * 4];
#pragma unroll
  for (int i = 0; i < RG * 4; ++i)
#pragma unroll
    for (int j = 0; j < CG * 4; ++j) acc[i][j] = 0.f;

  const int KF4 = BK / 4;
  const int NF4 = BN / 4;

  for (int k0 = 0; k0 < K; k0 += BK) {
#pragma unroll
    for (int j = tid; j < BM * KF4; j += 256) {
      int row = j / KF4, kq = j % KF4;
      float4 v = *(const float4*)&A[(size_t)(m0 + row) * lda + k0 + kq * 4];
      As[kq * 4 + 0][row] = v.x;
      As[kq * 4 + 1][row] = v.y;
      As[kq * 4 + 2][row] = v.z;
      As[kq * 4 + 3][row] = v.w;
    }
#pragma unroll
    for (int j = tid; j < BK * NF4; j += 256) {
      int row = j / NF4, nq = j % NF4;
      int c = n0 + nq * 4;
      float4 v;
      if (c + 3 < N) {
        v = *(const float4*)&B[(size_t)(k0 + row) * ldb + c];
      } else {
        const float* bp = &B[(size_t)(k0 + row) * ldb];
        v.x = (c + 0 < N) ? bp[c + 0] : 0.f;
        v.y = (c + 1 < N) ? bp[c + 1] : 0.f;
        v.z = (c + 2 < N) ? bp[c + 2] : 0.f;
        v.w = (c + 3 < N) ? bp[c + 3] : 0.f;
      }
      *(float4*)&Bs[row][nq * 4] = v;
    }
    __syncthreads();

#pragma unroll
    for (int k = 0; k < BK; ++k) {
      float a[RG][4], b[CG][4];
#pragma unroll
      for (int g = 0; g < RG; ++g) {
        float4 va = *(const float4*)&As[k][g * (BM / RG) + ty * 4];
        a[g][0] = va.x; a[g][1] = va.y; a[g][2] = va.z; a[g][3] = va.w;
      }
#pragma unroll
      for (int h = 0; h < CG; ++h) {
        float4 vb = *(const float4*)&Bs[k][h * (BN / CG) + tx * 4];
        b[h][0] = vb.x; b[h][1] = vb.y; b[h][2] = vb.z; b[h][3] = vb.w;
      }
#pragma unroll
      for (int g = 0; g < RG; ++g)
#pragma unroll
        for (int i = 0; i < 4; ++i)
#pragma unroll
          for (int h = 0; h < CG; ++h)
#pragma unroll
            for (int j = 0; j < 4; ++j)
              acc[g * 4 + i][h * 4 + j] =
                  fmaf(a[g][i], b[h][j], acc[g * 4 + i][h * 4 + j]);
    }
    __syncthreads();
  }

#pragma unroll
  for (int g = 0; g < RG; ++g) {
#pragma unroll
    for (int i = 0; i < 4; ++i) {
      int r = m0 + g * (BM / RG) + ty * 4 + i;
#pragma unroll
      for (int h = 0; h < CG; ++h) {
        int c = n0 + h * (BN / CG) + tx * 4;
        float4 v;
        v.x = acc[g * 4 + i][h * 4 + 0];
        v.y = acc[g * 4 + i][h * 4 + 1];
        v.z = acc[g * 4 + i][h * 4 + 2];
        v.w = acc[g * 4 + i][h * 4 + 3];
        if (c + 3 < N) {
          if (EPI == 1) {
            v.x = softplusf_(v.x + bias[c + 0]);
            v.y = softplusf_(v.y + bias[c + 1]);
            v.z = softplusf_(v.z + bias[c + 2]);
            v.w = softplusf_(v.w + bias[c + 3]);
          }
          *(float4*)&C[(size_t)r * ldc + c] = v;
        } else {
          float vv[4] = {v.x, v.y, v.z, v.w};
#pragma unroll
          for (int j = 0; j < 4; ++j)
            if (c + j < N) {
              float o = vv[j];
              if (EPI == 1) o = softplusf_(o + bias[c + j]);
              C[(size_t)r * ldc + c + j] = o;
            }
        }
      }
    }
  }
}

// ---------------------------------------------------------------------------
// Causal depthwise conv1d (k=4, left-pad 3) + bias + SiLU. xi [4096][2048].
// ---------------------------------------------------------------------------
__launch_bounds__(256)
__global__ void conv_silu(const float* __restrict__ xi,
                          const float* __restrict__ conv_w,
                          const float* __restrict__ conv_b,
                          float* __restrict__ xc)
{
  const int total = B_ * L_ * (DINNER / 4);
  for (int idx = blockIdx.x * blockDim.x + threadIdx.x; idx < total;
       idx += gridDim.x * blockDim.x) {
    int d4 = idx & (DINNER / 4 - 1);
    int l = (idx >> 9) & (L_ - 1);
    int b = idx >> 20;
    int d = d4 * 4;

    float w[4][4];
#pragma unroll
    for (int c = 0; c < 4; ++c) {
      float4 wv = *(const float4*)&conv_w[(d + c) * 4];
      w[c][0] = wv.x; w[c][1] = wv.y; w[c][2] = wv.z; w[c][3] = wv.w;
    }
    float4 bv = *(const float4*)&conv_b[d];
    float s[4] = {bv.x, bv.y, bv.z, bv.w};
#pragma unroll
    for (int t = 0; t < 4; ++t) {
      int ls = l - 3 + t;
      if (ls >= 0) {
        float4 xv = *(const float4*)&xi[(size_t)(b * L_ + ls) * DINNER + d];
        s[0] = fmaf(w[0][t], xv.x, s[0]);
        s[1] = fmaf(w[1][t], xv.y, s[1]);
        s[2] = fmaf(w[2][t], xv.z, s[2]);
        s[3] = fmaf(w[3][t], xv.w, s[3]);
      }
    }
    float4 o;
    o.x = s[0] * sigmoidf_(s[0]);
    o.y = s[1] * sigmoidf_(s[1]);
    o.z = s[2] * sigmoidf_(s[2]);
    o.w = s[3] * sigmoidf_(s[3]);
    *(float4*)&xc[(size_t)idx * 4] = o;
  }
}

// ---------------------------------------------------------------------------
// Chunked scan pass 1.
// ---------------------------------------------------------------------------
__launch_bounds__(256)
__global__ void scan_pass1(const float* __restrict__ delta,
                           const float* __restrict__ xc,
                           const float* __restrict__ xdbl,
                           const float* __restrict__ A_log,
                           float* __restrict__ Pbuf,
                           float* __restrict__ Qbuf)
{
  const int blk = blockIdx.x;
  const int b = blk >> 7;
  const int c = (blk >> 3) & (NC - 1);
  const int d = ((blk & 7) << 8) + threadIdx.x;

  float An[DSTATE];
#pragma unroll
  for (int n = 0; n < DSTATE; ++n) An[n] = -__expf(A_log[d * DSTATE + n]);

  __shared__ float bs[CL][DSTATE];
  const size_t bL = (size_t)b * L_;
  const int l0 = c * CL;
  for (int j = threadIdx.x; j < CL * 4; j += 256) {
    int step = j >> 2, q = j & 3;
    *(float4*)&bs[step][q * 4] =
        *(const float4*)&xdbl[(bL + l0 + step) * 96 + DTRANK + q * 4];
  }
  __syncthreads();

  float P[DSTATE], q[DSTATE];
#pragma unroll
  for (int n = 0; n < DSTATE; ++n) { P[n] = 1.f; q[n] = 0.f; }

  for (int i = 0; i < CL; ++i) {
    const size_t bl = bL + l0 + i;
    float dv = delta[bl * DINNER + d];
    float dx = dv * xc[bl * DINNER + d];
#pragma unroll
    for (int n = 0; n < DSTATE; ++n) {
      float dA = __expf(dv * An[n]);
      P[n] *= dA;
      q[n] = fmaf(dA, q[n], dx * bs[i][n]);
    }
  }
  const size_t base = (((size_t)b * NC + c) * DSTATE) * DINNER + d;
#pragma unroll
  for (int n = 0; n < DSTATE; ++n) {
    Pbuf[base + (size_t)n * DINNER] = P[n];
    Qbuf[base + (size_t)n * DINNER] = q[n];
  }
}

__launch_bounds__(256)
__global__ void scan_combine(const float* __restrict__ Pbuf,
                             const float* __restrict__ Qbuf,
                             float* __restrict__ Hini)
{
  const int idx = blockIdx.x * 256 + threadIdx.x;
  const int d = idx & (DINNER - 1);
  const int n = (idx >> 11) & (DSTATE - 1);
  const int b = idx >> 15;

  float h = 0.f;
#pragma unroll
  for (int c = 0; c < NC; ++c) {
    const size_t off = (((size_t)b * NC + c) * DSTATE + n) * DINNER + d;
    Hini[off] = h;
    h = fmaf(Pbuf[off], h, Qbuf[off]);
  }
}

// ---------------------------------------------------------------------------
// Chunked scan pass 2: re-scan from Hini, gate, emit yg as (hi,lo,hi) bf16
// triplets -> yg3 [4096][6144].
// ---------------------------------------------------------------------------
__launch_bounds__(256)
__global__ void scan_pass2(const float* __restrict__ delta,
                           const float* __restrict__ xc,
                           const float* __restrict__ res,
                           const float* __restrict__ xdbl,
                           const float* __restrict__ A_log,
                           const float* __restrict__ Dvec,
                           const float* __restrict__ Hini,
                           unsigned short* __restrict__ yg3)
{
  const int blk = blockIdx.x;
  const int b = blk >> 7;
  const int c = (blk >> 3) & (NC - 1);
  const int d = ((blk & 7) << 8) + threadIdx.x;

  float An[DSTATE];
#pragma unroll
  for (int n = 0; n < DSTATE; ++n) An[n] = -__expf(A_log[d * DSTATE + n]);
  const float Dd = Dvec[d];

  float h[DSTATE];
  const size_t base = (((size_t)b * NC + c) * DSTATE) * DINNER + d;
#pragma unroll
  for (int n = 0; n < DSTATE; ++n) h[n] = Hini[base + (size_t)n * DINNER];

  __shared__ float bc[CL][2 * DSTATE];
  const size_t bL = (size_t)b * L_;
  const int l0 = c * CL;
  for (int j = threadIdx.x; j < CL * 8; j += 256) {
    int step = j >> 3, q = j & 7;
    *(float4*)&bc[step][q * 4] =
        *(const float4*)&xdbl[(bL + l0 + step) * 96 + DTRANK + q * 4];
  }
  __syncthreads();

  for (int i = 0; i < CL; ++i) {
    const size_t bl = bL + l0 + i;
    float dv = delta[bl * DINNER + d];
    float xv = xc[bl * DINNER + d];
    float rv = res[bl * DINNER + d];
    float dx = dv * xv;
    float y = 0.f;
#pragma unroll
    for (int n = 0; n < DSTATE; ++n) {
      float dA = __expf(dv * An[n]);
      h[n] = fmaf(dA, h[n], dx * bc[i][n]);
      y = fmaf(h[n], bc[i][DSTATE + n], y);
    }
    float v = (y + xv * Dd) * (rv * sigmoidf_(rv));
    unsigned short hi = f2bf_rne(v);
    unsigned short lo = f2bf_rne(v - bf2f(hi));
    const size_t o = bl * 6144 + 3 * (size_t)d;
    yg3[o + 0] = hi; yg3[o + 1] = lo; yg3[o + 2] = hi;
  }
}

// ---------------------------------------------------------------------------
extern "C" void kernel_launch(void* const* d_in, const int* in_sizes, int n_in,
                              void* d_out, int out_size, void* d_ws,
                              size_t ws_size, hipStream_t stream)
{
  const float* x      = (const float*)d_in[0];
  const float* W_in   = (const float*)d_in[1];
  const float* conv_w = (const float*)d_in[2];
  const float* conv_b = (const float*)d_in[3];
  const float* W_x    = (const float*)d_in[4];
  const float* W_dt   = (const float*)d_in[5];
  const float* b_dt   = (const float*)d_in[6];
  const float* A_log  = (const float*)d_in[7];
  const float* Dv     = (const float*)d_in[8];
  const float* W_out  = (const float*)d_in[9];
  float* out = (float*)d_out;

  float* ws = (float*)d_ws;
  float* xi    = ws;                    // 8,388,608 f
  float* res   = ws + 8388608;          // 8,388,608 f
  float* xc    = ws + 16777216;         // 8,388,608 f
  float* xdbl  = ws + 25165824;         //   393,216 f
  float* Pbuf  = ws + 25559040;         // 1,048,576 f
  float* Qbuf  = ws + 26607616;         // 1,048,576 f
  float* Hini  = ws + 27656192;         // 1,048,576 f
  unsigned short* yg3      = (unsigned short*)(ws + 28704768);  // 4096*6144 us
  unsigned short* bt3_wout = (unsigned short*)(ws + 41287680);  // 1024*6144 us
  // aliases, live only until GEMM1 completes:
  unsigned short* a3_x     = (unsigned short*)(ws + 16777216);
  unsigned short* bt3_win  = (unsigned short*)(ws + 23068672);
  float* delta = ws;           // xi region, after conv & after partials
  float* part  = ws;           // GEMM3 split-K partials: [4][4096][96] f

  const int M = B_ * L_;  // 4096

  // 1) split x and W_in into 3-term bf16
  split_a3<<<4096, 256, 0, stream>>>(x, a3_x);
  split_bt3<<<dim3(4096 / 64, 1024 / 64), 256, 0, stream>>>(W_in, bt3_win,
                                                            1024, 4096);

  // 2) GEMM1 (MFMA): [4096,3072]x[3072,4096] -> xi (cols<2048) | res (rest)
  gemm_mfma_bf16<2048><<<dim3(32, 32), 256, 0, stream>>>(
      a3_x, bt3_win, xi, res, 4096, 3072);

  // 3) split W_out (for GEMM6 later)
  split_bt3<<<dim3(1024 / 64, 2048 / 64), 256, 0, stream>>>(W_out, bt3_wout,
                                                            2048, 1024);

  // 4) xc = silu(conv(xi) + conv_b)   (xi dead afterwards)
  conv_silu<<<4096, 256, 0, stream>>>(xi, conv_w, conv_b, xc);

  // 5) xdbl = xc @ W_x  via split-K (partials in dead xi region) + reduce
  gemm_wx_splitk<<<dim3(KS_, M / 16), 384, 0, stream>>>(xc, W_x, part);
  reduce_wx<<<384, 256, 0, stream>>>(part, xdbl);

  // 6) delta = softplus(xdbl[:,0:64] @ W_dt + b_dt)  (overwrites partials)
  gemm_f32<128, 128, 16, 2, 2, 1>
      <<<dim3(DINNER / 128, M / 128), 256, 0, stream>>>(
          xdbl, 96, W_dt, DINNER, delta, DINNER, M, DINNER, DTRANK, b_dt);

  // 7) chunked selective scan + gating -> yg3
  scan_pass1<<<B_ * NC * (DINNER / 256), 256, 0, stream>>>(
      delta, xc, xdbl, A_log, Pbuf, Qbuf);
  scan_combine<<<(B_ * DSTATE * DINNER) / 256, 256, 0, stream>>>(
      Pbuf, Qbuf, Hini);
  scan_pass2<<<B_ * NC * (DINNER / 256), 256, 0, stream>>>(
      delta, xc, res, xdbl, A_log, Dv, Hini, yg3);

  // 8) GEMM6 (MFMA): [4096,6144]x[6144,1024] -> out
  gemm_mfma_bf16<0><<<dim3(8, 32), 256, 0, stream>>>(
      yg3, bt3_wout, out, nullptr, 1024, 6144);
}

// Round 11
// 615.356 us; speedup vs baseline: 2.0991x; 1.1433x over previous
//
#include <hip/hip_runtime.h>
#include <hip/hip_bf16.h>
#include <cstdint>

// Mamba block fwd, B=2 L=2048 d_model=1024 d_inner=2048 n=16 dt_rank=64 d_conv=4
// Round 11 (from r10: 703.5us, absmax 0.03125):
//  - GEMM6 retiled BN=64 -> grid (16,32)=512 WGs (was 256 = 1 blk/CU).
//  - XCD-aware bijective block swizzle in both MFMA GEMMs.
//  - Scan NC 16->32 (CL=64): 512 blocks; P/Q alias into yg3 region (dead
//    until pass2), Hini in old slot -- no workspace growth.
//
// Workspace (float units), peak 169.5 MiB:
//   xi   @0          [4096][2048] f32  dead after conv; splitk partials;
//                    then delta (GEMM4 out)
//   res  @8388608    [4096][2048] f32   till pass2
//   xc   @16777216   [4096][2048] f32   till pass2
//   xdbl @25165824   [4096][96]  f32    till pass2
//   Hini @25559040   2M f (NC=32)
//   yg3  @28704768   [4096][6144] bf16 (48 MiB); P@28704768/Q@30801920
//                    (2M f each) alias its head until pass2 writes yg3
//   bt3_wout @41287680 [1024][6144] bf16 (12 MiB) till GEMM6
//   aliases (live only until GEMM1): a3_x @16777216, bt3_win @23068672

#define B_    2
#define L_    2048
#define DMODEL 1024
#define DINNER 2048
#define DSTATE 16
#define DTRANK 64
#define NC    32
#define CL    64

typedef short bf16x8 __attribute__((ext_vector_type(8)));
typedef float f32x4  __attribute__((ext_vector_type(4)));

__device__ __forceinline__ float sigmoidf_(float x) {
  return 1.f / (1.f + __expf(-x));
}
__device__ __forceinline__ float softplusf_(float x) {
  return fmaxf(x, 0.f) + log1pf(__expf(-fabsf(x)));
}
__device__ __forceinline__ unsigned short f2bf_rne(float x) {
  union { float f; unsigned int u; } v; v.f = x;
  unsigned int r = v.u + 0x7FFFu + ((v.u >> 16) & 1u);
  return (unsigned short)(r >> 16);
}
__device__ __forceinline__ float bf2f(unsigned short h) {
  union { float f; unsigned int u; } v; v.u = ((unsigned int)h) << 16;
  return v.f;
}
__device__ __forceinline__ void split3_a(float x, unsigned short* o) {
  unsigned short hi = f2bf_rne(x);
  unsigned short lo = f2bf_rne(x - bf2f(hi));
  o[0] = hi; o[1] = lo; o[2] = hi;
}
__device__ __forceinline__ void split3_b(float x, unsigned short* o) {
  unsigned short hi = f2bf_rne(x);
  unsigned short lo = f2bf_rne(x - bf2f(hi));
  o[0] = hi; o[1] = hi; o[2] = lo;
}

__device__ __forceinline__ void gload16(const void* g, void* l) {
  __builtin_amdgcn_global_load_lds(
      (const __attribute__((address_space(1))) void*)g,
      (__attribute__((address_space(3))) void*)l, 16, 0, 0);
}

// ---------------------------------------------------------------------------
// bf16 MFMA GEMM, m97-style, BM=128 fixed, BN in {64,128}.
// 4 waves 2x2; per-wave (64)x(BN/2) via 4xNR frags of 16x16x32.
// XCD swizzle: bijective remap of flat block id (requires nwg%8==0).
// Swizzle invariant (verified r9/r10 on HW, bank-conflict counter = 0):
// LDS chunk phys[row][c] holds global chunk (row, c^(row&7)).
// ---------------------------------------------------------------------------
template<int BN, int SPLITCOL>
__launch_bounds__(256)
__global__ void gemm_mfma_bf16(const unsigned short* __restrict__ A3,
                               const unsigned short* __restrict__ B3t,
                               float* __restrict__ outA,
                               float* __restrict__ outB,
                               int N, int K3)
{
  constexpr int NR = BN / 32;   // N-frags per wave
  __shared__ unsigned short As[128 * 64];
  __shared__ unsigned short Bs[BN * 64];

  const int tid  = threadIdx.x;
  const int lane = tid & 63;
  const int wid  = tid >> 6;
  const int wr   = wid >> 1;
  const int wc   = wid & 1;

  // XCD-aware bijective swizzle (nwg % 8 == 0 for both call sites)
  const int NX   = gridDim.x;
  const int nwg  = NX * gridDim.y;
  const int flat = blockIdx.y * NX + blockIdx.x;
  const int swz  = (flat & 7) * (nwg >> 3) + (flat >> 3);
  const int m0   = (swz / NX) * 128;
  const int n0   = (swz % NX) * BN;

  const int srow = lane >> 3;
  const int scol = ((lane & 7) ^ srow) * 8;

  const unsigned short* gA = A3 + (size_t)(m0 + wid * 8 + srow) * K3 + scol;
  const unsigned short* gB = B3t + (size_t)(n0 + wid * 8 + srow) * K3 + scol;
  const size_t rs32 = (size_t)32 * K3;

  unsigned short* lA = &As[wid * 8 * 64];
  unsigned short* lB = &Bs[wid * 8 * 64];

  f32x4 acc[4][NR];
#pragma unroll
  for (int i = 0; i < 4; ++i)
#pragma unroll
    for (int j = 0; j < NR; ++j) acc[i][j] = (f32x4){0.f, 0.f, 0.f, 0.f};

  const int KT = K3 >> 6;
  for (int kt = 0; kt < KT; ++kt) {
    const int k0 = kt << 6;
#pragma unroll
    for (int i = 0; i < 4; ++i)
      gload16(gA + i * rs32 + k0, lA + i * 32 * 64);
#pragma unroll
    for (int i = 0; i < BN / 32; ++i)
      gload16(gB + i * rs32 + k0, lB + i * 32 * 64);
    __syncthreads();

#pragma unroll
    for (int kk = 0; kk < 2; ++kk) {
      const int c16 = kk * 4 + (lane >> 4);
      bf16x8 a[4], b[NR];
#pragma unroll
      for (int rb = 0; rb < 4; ++rb) {
        const int row = wr * 64 + rb * 16 + (lane & 15);
        a[rb] = *(const bf16x8*)&As[row * 64 + ((c16 ^ (row & 7)) << 3)];
      }
#pragma unroll
      for (int nb = 0; nb < NR; ++nb) {
        const int col = wc * (BN / 2) + nb * 16 + (lane & 15);
        b[nb] = *(const bf16x8*)&Bs[col * 64 + ((c16 ^ (col & 7)) << 3)];
      }
#pragma unroll
      for (int rb = 0; rb < 4; ++rb)
#pragma unroll
        for (int nb = 0; nb < NR; ++nb)
          acc[rb][nb] = __builtin_amdgcn_mfma_f32_16x16x32_bf16(
              a[rb], b[nb], acc[rb][nb], 0, 0, 0);
    }
    __syncthreads();
  }

  const int crow0 = (lane >> 4) * 4;
  const int ccol  = lane & 15;
#pragma unroll
  for (int rb = 0; rb < 4; ++rb) {
#pragma unroll
    for (int nb = 0; nb < NR; ++nb) {
      const int gc = n0 + wc * (BN / 2) + nb * 16 + ccol;
#pragma unroll
      for (int j = 0; j < 4; ++j) {
        const int gr = m0 + wr * 64 + rb * 16 + crow0 + j;
        const float v = acc[rb][nb][j];
        if (SPLITCOL > 0) {
          if (gc < SPLITCOL) outA[(size_t)gr * SPLITCOL + gc] = v;
          else               outB[(size_t)gr * SPLITCOL + (gc - SPLITCOL)] = v;
        } else {
          outA[(size_t)gr * N + gc] = v;
        }
      }
    }
  }
}

// ---------------------------------------------------------------------------
// x [4096][1024] f32 -> a3_x [4096][3072] bf16 (hi,lo,hi).
// ---------------------------------------------------------------------------
__launch_bounds__(256)
__global__ void split_a3(const float* __restrict__ in,
                         unsigned short* __restrict__ out)
{
  const int idx = blockIdx.x * 256 + threadIdx.x;
  const int row = idx >> 8;
  const int q   = idx & 255;
  float4 v = *(const float4*)&in[(size_t)row * DMODEL + q * 4];
  unsigned short buf[12] __attribute__((aligned(8)));
  split3_a(v.x, &buf[0]);
  split3_a(v.y, &buf[3]);
  split3_a(v.z, &buf[6]);
  split3_a(v.w, &buf[9]);
  unsigned short* o = out + (size_t)row * 3072 + q * 12;
#pragma unroll
  for (int j = 0; j < 3; ++j)
    *(ushort4*)&o[j * 4] = *(const ushort4*)&buf[j * 4];
}

// ---------------------------------------------------------------------------
// B [K][N] f32 -> out [N][3K] bf16 (hi,hi,lo), transposed via LDS 64x64 tile.
// ---------------------------------------------------------------------------
__launch_bounds__(256)
__global__ void split_bt3(const float* __restrict__ B,
                          unsigned short* __restrict__ out,
                          int K, int N)
{
  __shared__ float T[64][65];
  const int n0 = blockIdx.x * 64;
  const int k0 = blockIdx.y * 64;
  const int t  = threadIdx.x;

  const int nl4 = (t & 15) * 4;
  const int klr = t >> 4;
#pragma unroll
  for (int i = 0; i < 4; ++i) {
    float4 v = *(const float4*)&B[(size_t)(k0 + klr + i * 16) * N + n0 + nl4];
    T[klr + i * 16][nl4 + 0] = v.x;
    T[klr + i * 16][nl4 + 1] = v.y;
    T[klr + i * 16][nl4 + 2] = v.z;
    T[klr + i * 16][nl4 + 3] = v.w;
  }
  __syncthreads();

  const int nl = t >> 2;
  const int kc = (t & 3) * 16;
  unsigned short buf[48] __attribute__((aligned(8)));
#pragma unroll
  for (int kk = 0; kk < 16; ++kk) split3_b(T[kc + kk][nl], &buf[kk * 3]);
  unsigned short* o = out + (size_t)(n0 + nl) * (3 * K) + 3 * (k0 + kc);
#pragma unroll
  for (int j = 0; j < 12; ++j)
    *(ushort4*)&o[j * 4] = *(const ushort4*)&buf[j * 4];
}

// ---------------------------------------------------------------------------
// xc@W_x split-K tall-skinny (verified r10): part[ks][4096][96].
// ---------------------------------------------------------------------------
#define KS_   4
#define KCH   (DINNER / KS_)   // 512
__launch_bounds__(384)
__global__ void gemm_wx_splitk(const float* __restrict__ xc,
                               const float* __restrict__ wx,
                               float* __restrict__ part)
{
  const int ks = blockIdx.x;
  const int m0 = blockIdx.y * 16;
  const int t  = threadIdx.x;
  const int r  = t / 24;
  const int c  = (t % 24) * 4;
  const int k0 = ks * KCH;

  const float* arow = xc + (size_t)(m0 + r) * DINNER + k0;
  const float* wp   = wx + (size_t)k0 * 96 + c;

  float ax = 0.f, ay = 0.f, az = 0.f, aw = 0.f;
  for (int k = 0; k < KCH; k += 4) {
    float4 a  = *(const float4*)&arow[k];
    float4 w0 = *(const float4*)&wp[(size_t)(k + 0) * 96];
    float4 w1 = *(const float4*)&wp[(size_t)(k + 1) * 96];
    float4 w2 = *(const float4*)&wp[(size_t)(k + 2) * 96];
    float4 w3 = *(const float4*)&wp[(size_t)(k + 3) * 96];
    ax = fmaf(a.x, w0.x, ax); ax = fmaf(a.y, w1.x, ax);
    ax = fmaf(a.z, w2.x, ax); ax = fmaf(a.w, w3.x, ax);
    ay = fmaf(a.x, w0.y, ay); ay = fmaf(a.y, w1.y, ay);
    ay = fmaf(a.z, w2.y, ay); ay = fmaf(a.w, w3.y, ay);
    az = fmaf(a.x, w0.z, az); az = fmaf(a.y, w1.z, az);
    az = fmaf(a.z, w2.z, az); az = fmaf(a.w, w3.z, az);
    aw = fmaf(a.x, w0.w, aw); aw = fmaf(a.y, w1.w, aw);
    aw = fmaf(a.z, w2.w, aw); aw = fmaf(a.w, w3.w, aw);
  }
  float4 o = {ax, ay, az, aw};
  *(float4*)&part[((size_t)ks * 4096 + m0 + r) * 96 + c] = o;
}

__launch_bounds__(256)
__global__ void reduce_wx(const float* __restrict__ part,
                          float* __restrict__ xdbl)
{
  const int i = blockIdx.x * 256 + threadIdx.x;
  const size_t S = (size_t)4096 * 96 / 4;
  const float4* p = (const float4*)part;
  float4 a = p[i];
  float4 b = p[i + S];
  float4 c = p[i + 2 * S];
  float4 d = p[i + 3 * S];
  float4 o;
  o.x = (a.x + b.x) + (c.x + d.x);
  o.y = (a.y + b.y) + (c.y + d.y);
  o.z = (a.z + b.z) + (c.z + d.z);
  o.w = (a.w + b.w) + (c.w + d.w);
  ((float4*)xdbl)[i] = o;
}

// ---------------------------------------------------------------------------
// fp32 tiled GEMM (GEMM4 only). EPI: 1 = softplus(acc+bias).
// ---------------------------------------------------------------------------
template<int BM, int BN, int BK, int RG, int CG, int EPI>
__launch_bounds__(256)
__global__ void gemm_f32(const float* __restrict__ A, int lda,
                         const float* __restrict__ B, int ldb,
                         float* __restrict__ C, int ldc,
                         int M, int N, int K,
                         const float* __restrict__ bias)
{
  __shared__ float As[BK][BM + 4];
  __shared__ float Bs[BK][BN + 4];

  const int tid = threadIdx.x;
  const int tx = tid & 15;
  const int ty = tid >> 4;
  const int m0 = blockIdx.y * BM;
  const int n0 = blockIdx.x * BN;

  float acc[RG * 4][CG * 4];
#pragma unroll
  for (int i = 0; i < RG * 4; ++i)
#pragma unroll
    for (int j = 0; j < CG * 4; ++j) acc[i][j] = 0.f;

  const int KF4 = BK / 4;
  const int NF4 = BN / 4;

  for (int k0 = 0; k0 < K; k0 += BK) {
#pragma unroll
    for (int j = tid; j < BM * KF4; j += 256) {
      int row = j / KF4, kq = j % KF4;
      float4 v = *(const float4*)&A[(size_t)(m0 + row) * lda + k0 + kq * 4];
      As[kq * 4 + 0][row] = v.x;
      As[kq * 4 + 1][row] = v.y;
      As[kq * 4 + 2][row] = v.z;
      As[kq * 4 + 3][row] = v.w;
    }
#pragma unroll
    for (int j = tid; j < BK * NF4; j += 256) {
      int row = j / NF4, nq = j % NF4;
      int c = n0 + nq * 4;
      float4 v;
      if (c + 3 < N) {
        v = *(const float4*)&B[(size_t)(k0 + row) * ldb + c];
      } else {
        const float* bp = &B[(size_t)(k0 + row) * ldb];
        v.x = (c + 0 < N) ? bp[c + 0] : 0.f;
        v.y = (c + 1 < N) ? bp[c + 1] : 0.f;
        v.z = (c + 2 < N) ? bp[c + 2] : 0.f;
        v.w = (c + 3 < N) ? bp[c + 3] : 0.f;
      }
      *(float4*)&Bs[row][nq * 4] = v;
    }
    __syncthreads();

#pragma unroll
    for (int k = 0; k < BK; ++k) {
      float a[RG][4], b[CG][4];
#pragma unroll
      for (int g = 0; g < RG; ++g) {
        float4 va = *(const float4*)&As[k][g * (BM / RG) + ty * 4];
        a[g][0] = va.x; a[g][1] = va.y; a[g][2] = va.z; a[g][3] = va.w;
      }
#pragma unroll
      for (int h = 0; h < CG; ++h) {
        float4 vb = *(const float4*)&Bs[k][h * (BN / CG) + tx * 4];
        b[h][0] = vb.x; b[h][1] = vb.y; b[h][2] = vb.z; b[h][3] = vb.w;
      }
#pragma unroll
      for (int g = 0; g < RG; ++g)
#pragma unroll
        for (int i = 0; i < 4; ++i)
#pragma unroll
          for (int h = 0; h < CG; ++h)
#pragma unroll
            for (int j = 0; j < 4; ++j)
              acc[g * 4 + i][h * 4 + j] =
                  fmaf(a[g][i], b[h][j], acc[g * 4 + i][h * 4 + j]);
    }
    __syncthreads();
  }

#pragma unroll
  for (int g = 0; g < RG; ++g) {
#pragma unroll
    for (int i = 0; i < 4; ++i) {
      int r = m0 + g * (BM / RG) + ty * 4 + i;
#pragma unroll
      for (int h = 0; h < CG; ++h) {
        int c = n0 + h * (BN / CG) + tx * 4;
        float4 v;
        v.x = acc[g * 4 + i][h * 4 + 0];
        v.y = acc[g * 4 + i][h * 4 + 1];
        v.z = acc[g * 4 + i][h * 4 + 2];
        v.w = acc[g * 4 + i][h * 4 + 3];
        if (c + 3 < N) {
          if (EPI == 1) {
            v.x = softplusf_(v.x + bias[c + 0]);
            v.y = softplusf_(v.y + bias[c + 1]);
            v.z = softplusf_(v.z + bias[c + 2]);
            v.w = softplusf_(v.w + bias[c + 3]);
          }
          *(float4*)&C[(size_t)r * ldc + c] = v;
        } else {
          float vv[4] = {v.x, v.y, v.z, v.w};
#pragma unroll
          for (int j = 0; j < 4; ++j)
            if (c + j < N) {
              float o = vv[j];
              if (EPI == 1) o = softplusf_(o + bias[c + j]);
              C[(size_t)r * ldc + c + j] = o;
            }
        }
      }
    }
  }
}

// ---------------------------------------------------------------------------
// Causal depthwise conv1d (k=4, left-pad 3) + bias + SiLU. xi [4096][2048].
// ---------------------------------------------------------------------------
__launch_bounds__(256)
__global__ void conv_silu(const float* __restrict__ xi,
                          const float* __restrict__ conv_w,
                          const float* __restrict__ conv_b,
                          float* __restrict__ xc)
{
  const int total = B_ * L_ * (DINNER / 4);
  for (int idx = blockIdx.x * blockDim.x + threadIdx.x; idx < total;
       idx += gridDim.x * blockDim.x) {
    int d4 = idx & (DINNER / 4 - 1);
    int l = (idx >> 9) & (L_ - 1);
    int b = idx >> 20;
    int d = d4 * 4;

    float w[4][4];
#pragma unroll
    for (int c = 0; c < 4; ++c) {
      float4 wv = *(const float4*)&conv_w[(d + c) * 4];
      w[c][0] = wv.x; w[c][1] = wv.y; w[c][2] = wv.z; w[c][3] = wv.w;
    }
    float4 bv = *(const float4*)&conv_b[d];
    float s[4] = {bv.x, bv.y, bv.z, bv.w};
#pragma unroll
    for (int t = 0; t < 4; ++t) {
      int ls = l - 3 + t;
      if (ls >= 0) {
        float4 xv = *(const float4*)&xi[(size_t)(b * L_ + ls) * DINNER + d];
        s[0] = fmaf(w[0][t], xv.x, s[0]);
        s[1] = fmaf(w[1][t], xv.y, s[1]);
        s[2] = fmaf(w[2][t], xv.z, s[2]);
        s[3] = fmaf(w[3][t], xv.w, s[3]);
      }
    }
    float4 o;
    o.x = s[0] * sigmoidf_(s[0]);
    o.y = s[1] * sigmoidf_(s[1]);
    o.z = s[2] * sigmoidf_(s[2]);
    o.w = s[3] * sigmoidf_(s[3]);
    *(float4*)&xc[(size_t)idx * 4] = o;
  }
}

// ---------------------------------------------------------------------------
// Chunked scan pass 1 (NC=32, CL=64). blk = b*256 + c*8 + dblk.
// ---------------------------------------------------------------------------
__launch_bounds__(256)
__global__ void scan_pass1(const float* __restrict__ delta,
                           const float* __restrict__ xc,
                           const float* __restrict__ xdbl,
                           const float* __restrict__ A_log,
                           float* __restrict__ Pbuf,
                           float* __restrict__ Qbuf)
{
  const int blk = blockIdx.x;
  const int b = blk >> 8;
  const int c = (blk >> 3) & (NC - 1);
  const int d = ((blk & 7) << 8) + threadIdx.x;

  float An[DSTATE];
#pragma unroll
  for (int n = 0; n < DSTATE; ++n) An[n] = -__expf(A_log[d * DSTATE + n]);

  __shared__ float bs[CL][DSTATE];
  const size_t bL = (size_t)b * L_;
  const int l0 = c * CL;
  for (int j = threadIdx.x; j < CL * 4; j += 256) {
    int step = j >> 2, q = j & 3;
    *(float4*)&bs[step][q * 4] =
        *(const float4*)&xdbl[(bL + l0 + step) * 96 + DTRANK + q * 4];
  }
  __syncthreads();

  float P[DSTATE], q[DSTATE];
#pragma unroll
  for (int n = 0; n < DSTATE; ++n) { P[n] = 1.f; q[n] = 0.f; }

  for (int i = 0; i < CL; ++i) {
    const size_t bl = bL + l0 + i;
    float dv = delta[bl * DINNER + d];
    float dx = dv * xc[bl * DINNER + d];
#pragma unroll
    for (int n = 0; n < DSTATE; ++n) {
      float dA = __expf(dv * An[n]);
      P[n] *= dA;
      q[n] = fmaf(dA, q[n], dx * bs[i][n]);
    }
  }
  const size_t base = (((size_t)b * NC + c) * DSTATE) * DINNER + d;
#pragma unroll
  for (int n = 0; n < DSTATE; ++n) {
    Pbuf[base + (size_t)n * DINNER] = P[n];
    Qbuf[base + (size_t)n * DINNER] = q[n];
  }
}

__launch_bounds__(256)
__global__ void scan_combine(const float* __restrict__ Pbuf,
                             const float* __restrict__ Qbuf,
                             float* __restrict__ Hini)
{
  const int idx = blockIdx.x * 256 + threadIdx.x;
  const int d = idx & (DINNER - 1);
  const int n = (idx >> 11) & (DSTATE - 1);
  const int b = idx >> 15;

  float h = 0.f;
#pragma unroll
  for (int c = 0; c < NC; ++c) {
    const size_t off = (((size_t)b * NC + c) * DSTATE + n) * DINNER + d;
    Hini[off] = h;
    h = fmaf(Pbuf[off], h, Qbuf[off]);
  }
}

// ---------------------------------------------------------------------------
// Chunked scan pass 2 (NC=32, CL=64): gate, emit (hi,lo,hi) bf16 -> yg3.
// ---------------------------------------------------------------------------
__launch_bounds__(256)
__global__ void scan_pass2(const float* __restrict__ delta,
                           const float* __restrict__ xc,
                           const float* __restrict__ res,
                           const float* __restrict__ xdbl,
                           const float* __restrict__ A_log,
                           const float* __restrict__ Dvec,
                           const float* __restrict__ Hini,
                           unsigned short* __restrict__ yg3)
{
  const int blk = blockIdx.x;
  const int b = blk >> 8;
  const int c = (blk >> 3) & (NC - 1);
  const int d = ((blk & 7) << 8) + threadIdx.x;

  float An[DSTATE];
#pragma unroll
  for (int n = 0; n < DSTATE; ++n) An[n] = -__expf(A_log[d * DSTATE + n]);
  const float Dd = Dvec[d];

  float h[DSTATE];
  const size_t base = (((size_t)b * NC + c) * DSTATE) * DINNER + d;
#pragma unroll
  for (int n = 0; n < DSTATE; ++n) h[n] = Hini[base + (size_t)n * DINNER];

  __shared__ float bc[CL][2 * DSTATE];
  const size_t bL = (size_t)b * L_;
  const int l0 = c * CL;
  for (int j = threadIdx.x; j < CL * 8; j += 256) {
    int step = j >> 3, q = j & 7;
    *(float4*)&bc[step][q * 4] =
        *(const float4*)&xdbl[(bL + l0 + step) * 96 + DTRANK + q * 4];
  }
  __syncthreads();

  for (int i = 0; i < CL; ++i) {
    const size_t bl = bL + l0 + i;
    float dv = delta[bl * DINNER + d];
    float xv = xc[bl * DINNER + d];
    float rv = res[bl * DINNER + d];
    float dx = dv * xv;
    float y = 0.f;
#pragma unroll
    for (int n = 0; n < DSTATE; ++n) {
      float dA = __expf(dv * An[n]);
      h[n] = fmaf(dA, h[n], dx * bc[i][n]);
      y = fmaf(h[n], bc[i][DSTATE + n], y);
    }
    float v = (y + xv * Dd) * (rv * sigmoidf_(rv));
    unsigned short hi = f2bf_rne(v);
    unsigned short lo = f2bf_rne(v - bf2f(hi));
    const size_t o = bl * 6144 + 3 * (size_t)d;
    yg3[o + 0] = hi; yg3[o + 1] = lo; yg3[o + 2] = hi;
  }
}

// ---------------------------------------------------------------------------
extern "C" void kernel_launch(void* const* d_in, const int* in_sizes, int n_in,
                              void* d_out, int out_size, void* d_ws,
                              size_t ws_size, hipStream_t stream)
{
  const float* x      = (const float*)d_in[0];
  const float* W_in   = (const float*)d_in[1];
  const float* conv_w = (const float*)d_in[2];
  const float* conv_b = (const float*)d_in[3];
  const float* W_x    = (const float*)d_in[4];
  const float* W_dt   = (const float*)d_in[5];
  const float* b_dt   = (const float*)d_in[6];
  const float* A_log  = (const float*)d_in[7];
  const float* Dv     = (const float*)d_in[8];
  const float* W_out  = (const float*)d_in[9];
  float* out = (float*)d_out;

  float* ws = (float*)d_ws;
  float* xi    = ws;                    // 8,388,608 f
  float* res   = ws + 8388608;          // 8,388,608 f
  float* xc    = ws + 16777216;         // 8,388,608 f
  float* xdbl  = ws + 25165824;         //   393,216 f
  float* Hini  = ws + 25559040;         // 2,097,152 f (NC=32)
  unsigned short* yg3      = (unsigned short*)(ws + 28704768);  // 4096*6144 us
  float* Pbuf  = ws + 28704768;         // 2,097,152 f (aliases yg3 head)
  float* Qbuf  = ws + 30801920;         // 2,097,152 f (aliases yg3)
  unsigned short* bt3_wout = (unsigned short*)(ws + 41287680);  // 1024*6144 us
  // aliases, live only until GEMM1 completes:
  unsigned short* a3_x     = (unsigned short*)(ws + 16777216);
  unsigned short* bt3_win  = (unsigned short*)(ws + 23068672);
  float* delta = ws;           // xi region, after conv & after partials
  float* part  = ws;           // splitk partials [4][4096][96]

  const int M = B_ * L_;  // 4096

  // 1) split x and W_in into 3-term bf16
  split_a3<<<4096, 256, 0, stream>>>(x, a3_x);
  split_bt3<<<dim3(4096 / 64, 1024 / 64), 256, 0, stream>>>(W_in, bt3_win,
                                                            1024, 4096);

  // 2) GEMM1 (MFMA, BN=128): [4096,3072]x[3072,4096] -> xi | res
  gemm_mfma_bf16<128, 2048><<<dim3(32, 32), 256, 0, stream>>>(
      a3_x, bt3_win, xi, res, 4096, 3072);

  // 3) split W_out
  split_bt3<<<dim3(1024 / 64, 2048 / 64), 256, 0, stream>>>(W_out, bt3_wout,
                                                            2048, 1024);

  // 4) xc = silu(conv(xi) + conv_b)
  conv_silu<<<4096, 256, 0, stream>>>(xi, conv_w, conv_b, xc);

  // 5) xdbl = xc @ W_x  via split-K + reduce
  gemm_wx_splitk<<<dim3(KS_, M / 16), 384, 0, stream>>>(xc, W_x, part);
  reduce_wx<<<384, 256, 0, stream>>>(part, xdbl);

  // 6) delta = softplus(xdbl[:,0:64] @ W_dt + b_dt)
  gemm_f32<128, 128, 16, 2, 2, 1>
      <<<dim3(DINNER / 128, M / 128), 256, 0, stream>>>(
          xdbl, 96, W_dt, DINNER, delta, DINNER, M, DINNER, DTRANK, b_dt);

  // 7) chunked selective scan (NC=32) + gating -> yg3
  scan_pass1<<<B_ * NC * (DINNER / 256), 256, 0, stream>>>(
      delta, xc, xdbl, A_log, Pbuf, Qbuf);
  scan_combine<<<(B_ * DSTATE * DINNER) / 256, 256, 0, stream>>>(
      Pbuf, Qbuf, Hini);
  scan_pass2<<<B_ * NC * (DINNER / 256), 256, 0, stream>>>(
      delta, xc, res, xdbl, A_log, Dv, Hini, yg3);

  // 8) GEMM6 (MFMA, BN=64): [4096,6144]x[6144,1024] -> out
  gemm_mfma_bf16<64, 0><<<dim3(16, 32), 256, 0, stream>>>(
      yg3, bt3_wout, out, nullptr, 1024, 6144);
}